// Round 1
// baseline (265.352 us; speedup 1.0000x reference)
//
#include <hip/hip_runtime.h>
#include <hip/hip_bf16.h>
#include <cstdint>

typedef __attribute__((ext_vector_type(8))) short short8;
typedef __attribute__((ext_vector_type(4))) float f32x4;
typedef unsigned short ushort_t;

#define S_LEN 2048
#define D_DIM 1024
#define NH 16
#define DK 64
#define BATCH 2
#define M_ROWS (BATCH * S_LEN)   // 4096

__device__ inline ushort_t f2bf(float f) {
    union { float f; uint32_t u; } v; v.f = f;
    uint32_t r = v.u + 0x7fffu + ((v.u >> 16) & 1u);  // RNE
    return (ushort_t)(r >> 16);
}

// ---------------- fp32 -> bf16 convert (vectorized) ----------------
__global__ void cvt_bf16(const float* __restrict__ in, ushort_t* __restrict__ out, int n4) {
    int i = blockIdx.x * blockDim.x + threadIdx.x;
    int stride = gridDim.x * blockDim.x;
    for (int idx = i; idx < n4; idx += stride) {
        float4 v = ((const float4*)in)[idx];
        ushort4 o;
        o.x = f2bf(v.x); o.y = f2bf(v.y); o.z = f2bf(v.z); o.w = f2bf(v.w);
        ((ushort4*)out)[idx] = o;
    }
}

// ---------------- GEMM: C[M,N] = A[M,K] * Bw[N,K]^T + bias[N] ----------------
// MODE 0: bf16 out, layout [b,h,s,dk]   (Q, K)
// MODE 1: bf16 out, layout [b,h,dk,s]   (V transposed)
// MODE 2: fp32 out, plain row-major [M,N] (final)
#define BM 128
#define BN 128
#define BK 32
#define LDT 40   // 32 + 8 pad (keeps 16B alignment, 2-way max conflict)

template<int MODE>
__global__ __launch_bounds__(256) void gemm_bt(const ushort_t* __restrict__ A,
                                               const ushort_t* __restrict__ Bw,
                                               const float* __restrict__ bias,
                                               void* __restrict__ Cout,
                                               int M, int N, int K) {
    __shared__ ushort_t As[BM * LDT];
    __shared__ ushort_t Bs[BN * LDT];
    int tid = threadIdx.x;
    int lane = tid & 63;
    int w = tid >> 6;
    int wr = w >> 1, wc = w & 1;
    int ntile = N / BN;
    int m0 = (blockIdx.x / ntile) * BM;
    int n0 = (blockIdx.x % ntile) * BN;

    int srow = tid >> 2;          // 0..63
    int scol = (tid & 3) * 8;     // 0,8,16,24

    f32x4 acc[4][4] = {};
    int lr = lane & 15;
    int lk = (lane >> 4) * 8;

    for (int kt = 0; kt < K; kt += BK) {
        __syncthreads();
        *(uint4*)&As[srow * LDT + scol]        = *(const uint4*)&A[(m0 + srow) * K + kt + scol];
        *(uint4*)&As[(srow + 64) * LDT + scol] = *(const uint4*)&A[(m0 + srow + 64) * K + kt + scol];
        *(uint4*)&Bs[srow * LDT + scol]        = *(const uint4*)&Bw[(n0 + srow) * K + kt + scol];
        *(uint4*)&Bs[(srow + 64) * LDT + scol] = *(const uint4*)&Bw[(n0 + srow + 64) * K + kt + scol];
        __syncthreads();

        short8 af[4], bf[4];
#pragma unroll
        for (int f = 0; f < 4; f++)
            af[f] = *(const short8*)&As[(wr * 64 + f * 16 + lr) * LDT + lk];
#pragma unroll
        for (int f = 0; f < 4; f++)
            bf[f] = *(const short8*)&Bs[(wc * 64 + f * 16 + lr) * LDT + lk];
#pragma unroll
        for (int i = 0; i < 4; i++)
#pragma unroll
            for (int j = 0; j < 4; j++)
                acc[i][j] = __builtin_amdgcn_mfma_f32_16x16x32_bf16(af[i], bf[j], acc[i][j], 0, 0, 0);
    }

    // epilogue: C row = m0 + wr*64 + i*16 + (lane>>4)*4 + r ; col = n0 + wc*64 + j*16 + (lane&15)
    int r0 = (lane >> 4) * 4;
#pragma unroll
    for (int j = 0; j < 4; j++) {
        int ncol = n0 + wc * 64 + j * 16 + lr;
        float bv = bias[ncol];
#pragma unroll
        for (int i = 0; i < 4; i++) {
            int mbase = m0 + wr * 64 + i * 16 + r0;
#pragma unroll
            for (int r = 0; r < 4; r++) {
                int mm = mbase + r;
                float v = acc[i][j][r] + bv;
                if (MODE == 2) {
                    ((float*)Cout)[(size_t)mm * N + ncol] = v;
                } else {
                    int bb = mm >> 11, ss = mm & 2047;
                    int hh = ncol >> 6, dk = ncol & 63;
                    size_t idx;
                    if (MODE == 0) idx = ((size_t)(bb * NH + hh) * S_LEN + ss) * DK + dk;
                    else           idx = ((size_t)(bb * NH + hh) * DK + dk) * S_LEN + ss;
                    ((ushort_t*)Cout)[idx] = f2bf(v);
                }
            }
        }
    }
}

// ---------------- Flash attention (causal) ----------------
// Q,K layout [b,h,s,dk]; Vt layout [b,h,dk,s]; out bf16 [b,s,h*dk]
// block: 256 thr (4 waves), 64 q rows (16/wave), kv tiles of 64
#define LKV 72   // 64 + 8 pad

__global__ __launch_bounds__(256) void attn_fwd(const ushort_t* __restrict__ Q,
                                                const ushort_t* __restrict__ K,
                                                const ushort_t* __restrict__ Vt,
                                                ushort_t* __restrict__ Oa) {
    __shared__ ushort_t Ks[64][LKV];
    __shared__ ushort_t Vs[64][LKV];
    __shared__ ushort_t Ps[4][16][LKV];

    int tid = threadIdx.x;
    int lane = tid & 63;
    int w = tid >> 6;
    int qt = blockIdx.x;
    int bh = blockIdx.y;
    size_t base = (size_t)bh * S_LEN * DK;
    int q0 = qt * 64;

    int lr = lane & 15;
    int lk = (lane >> 4) * 8;
    int r0 = (lane >> 4) * 4;

    // Q fragments (row = q0 + w*16 + lr, k slices 0:32 / 32:64)
    int qrow = q0 + w * 16 + lr;
    short8 qf0 = *(const short8*)&Q[base + (size_t)qrow * DK + lk];
    short8 qf1 = *(const short8*)&Q[base + (size_t)qrow * DK + 32 + lk];

    f32x4 o[4] = {};
    float mrow[4], lrow[4];
#pragma unroll
    for (int i = 0; i < 4; i++) { mrow[i] = -1e30f; lrow[i] = 0.f; }

    int srow = tid >> 3;          // 0..31
    int scol = (tid & 7) * 8;     // 0..56

    const float LOG2E = 1.44269504f;
    const float sc = 0.125f;      // 1/sqrt(64)

    for (int kvt = 0; kvt <= qt; ++kvt) {
        int kv0 = kvt * 64;
        __syncthreads();
        *(uint4*)&Ks[srow][scol]      = *(const uint4*)&K[base + (size_t)(kv0 + srow) * DK + scol];
        *(uint4*)&Ks[srow + 32][scol] = *(const uint4*)&K[base + (size_t)(kv0 + srow + 32) * DK + scol];
        *(uint4*)&Vs[srow][scol]      = *(const uint4*)&Vt[base + (size_t)srow * S_LEN + kv0 + scol];
        *(uint4*)&Vs[srow + 32][scol] = *(const uint4*)&Vt[base + (size_t)(srow + 32) * S_LEN + kv0 + scol];
        __syncthreads();

        // S = Q Kt : 4 kv-blocks of 16
        f32x4 s[4] = {};
#pragma unroll
        for (int n = 0; n < 4; n++) {
            short8 kf0 = *(const short8*)&Ks[n * 16 + lr][lk];
            short8 kf1 = *(const short8*)&Ks[n * 16 + lr][32 + lk];
            s[n] = __builtin_amdgcn_mfma_f32_16x16x32_bf16(qf0, kf0, s[n], 0, 0, 0);
            s[n] = __builtin_amdgcn_mfma_f32_16x16x32_bf16(qf1, kf1, s[n], 0, 0, 0);
        }

        // scale + causal mask (only diagonal tile needs masking)
        if (kvt == qt) {
#pragma unroll
            for (int n = 0; n < 4; n++)
#pragma unroll
                for (int i = 0; i < 4; i++) {
                    int qq = w * 16 + r0 + i;
                    int kk = n * 16 + lr;
                    s[n][i] = (kk <= qq) ? s[n][i] * sc : -1e30f;
                }
        } else {
#pragma unroll
            for (int n = 0; n < 4; n++)
#pragma unroll
                for (int i = 0; i < 4; i++) s[n][i] *= sc;
        }

        // online softmax: row stats over 4 regs x 16 lanes
        float corr[4];
#pragma unroll
        for (int i = 0; i < 4; i++) {
            float mx = fmaxf(fmaxf(s[0][i], s[1][i]), fmaxf(s[2][i], s[3][i]));
            mx = fmaxf(mx, __shfl_xor(mx, 1));
            mx = fmaxf(mx, __shfl_xor(mx, 2));
            mx = fmaxf(mx, __shfl_xor(mx, 4));
            mx = fmaxf(mx, __shfl_xor(mx, 8));
            float mnew = fmaxf(mrow[i], mx);
            corr[i] = exp2f((mrow[i] - mnew) * LOG2E);
            mrow[i] = mnew;
        }
        float psum[4] = {0.f, 0.f, 0.f, 0.f};
#pragma unroll
        for (int n = 0; n < 4; n++)
#pragma unroll
            for (int i = 0; i < 4; i++) {
                float p = exp2f((s[n][i] - mrow[i]) * LOG2E);
                s[n][i] = p;
                psum[i] += p;
            }
#pragma unroll
        for (int i = 0; i < 4; i++) {
            float ps = psum[i];
            ps += __shfl_xor(ps, 1);
            ps += __shfl_xor(ps, 2);
            ps += __shfl_xor(ps, 4);
            ps += __shfl_xor(ps, 8);
            lrow[i] = lrow[i] * corr[i] + ps;
        }
#pragma unroll
        for (int d = 0; d < 4; d++)
#pragma unroll
            for (int i = 0; i < 4; i++) o[d][i] *= corr[i];

        // P -> per-wave LDS (wave-internal, DS ops are in-order: no barrier)
#pragma unroll
        for (int n = 0; n < 4; n++)
#pragma unroll
            for (int i = 0; i < 4; i++)
                Ps[w][r0 + i][n * 16 + lr] = f2bf(s[n][i]);

        // O += P V : dk blocks of 16, kv slices of 32
#pragma unroll
        for (int d = 0; d < 4; d++) {
#pragma unroll
            for (int ks = 0; ks < 2; ks++) {
                short8 pf = *(const short8*)&Ps[w][lr][ks * 32 + lk];
                short8 vf = *(const short8*)&Vs[d * 16 + lr][ks * 32 + lk];
                o[d] = __builtin_amdgcn_mfma_f32_16x16x32_bf16(pf, vf, o[d], 0, 0, 0);
            }
        }
    }

    // epilogue: out[b, s, h*64+dk] bf16
    int b = bh >> 4, h = bh & 15;
#pragma unroll
    for (int d = 0; d < 4; d++)
#pragma unroll
        for (int i = 0; i < 4; i++) {
            int qq = q0 + w * 16 + r0 + i;
            int dk = d * 16 + lr;
            float v = o[d][i] / lrow[i];
            size_t idx = ((size_t)(b * S_LEN + qq)) * D_DIM + h * DK + dk;
            Oa[idx] = f2bf(v);
        }
}

// ---------------- launch ----------------
extern "C" void kernel_launch(void* const* d_in, const int* in_sizes, int n_in,
                              void* d_out, int out_size, void* d_ws, size_t ws_size,
                              hipStream_t stream) {
    const float* X  = (const float*)d_in[0];
    const float* Wq = (const float*)d_in[1];
    const float* bq = (const float*)d_in[2];
    const float* Wk = (const float*)d_in[3];
    const float* bk = (const float*)d_in[4];
    const float* Wv = (const float*)d_in[5];
    const float* bv = (const float*)d_in[6];
    const float* Wo = (const float*)d_in[7];
    const float* bo = (const float*)d_in[8];
    float* out = (float*)d_out;

    char* ws = (char*)d_ws;
    ushort_t* Xb  = (ushort_t*)ws;                          // 8 MiB [M,D] bf16
    ushort_t* Wb  = (ushort_t*)(ws + (8u  << 20));          // 2 MiB reused per weight
    ushort_t* Qb  = (ushort_t*)(ws + (10u << 20));          // 8 MiB [b,h,s,dk]
    ushort_t* Kb  = (ushort_t*)(ws + (18u << 20));          // 8 MiB [b,h,s,dk]
    ushort_t* Vtb = (ushort_t*)(ws + (26u << 20));          // 8 MiB [b,h,dk,s]
    ushort_t* Ab  = Xb;                                     // attn out reuses X slot

    const int M = M_ROWS, N = D_DIM, Kdim = D_DIM;
    dim3 cblk(256), cgrid(1024);
    int nX4 = (M * D_DIM) / 4;
    int nW4 = (D_DIM * D_DIM) / 4;
    dim3 ggrid((M / BM) * (N / BN));   // 256 blocks

    cvt_bf16<<<cgrid, cblk, 0, stream>>>(X, Xb, nX4);

    cvt_bf16<<<cgrid, cblk, 0, stream>>>(Wq, Wb, nW4);
    gemm_bt<0><<<ggrid, 256, 0, stream>>>(Xb, Wb, bq, Qb, M, N, Kdim);

    cvt_bf16<<<cgrid, cblk, 0, stream>>>(Wk, Wb, nW4);
    gemm_bt<0><<<ggrid, 256, 0, stream>>>(Xb, Wb, bk, Kb, M, N, Kdim);

    cvt_bf16<<<cgrid, cblk, 0, stream>>>(Wv, Wb, nW4);
    gemm_bt<1><<<ggrid, 256, 0, stream>>>(Xb, Wb, bv, Vtb, M, N, Kdim);

    dim3 agrid(S_LEN / 64, BATCH * NH);  // (32, 32)
    attn_fwd<<<agrid, 256, 0, stream>>>(Qb, Kb, Vtb, Ab);

    cvt_bf16<<<cgrid, cblk, 0, stream>>>(Wo, Wb, nW4);
    gemm_bt<2><<<ggrid, 256, 0, stream>>>(Ab, Wb, bo, out, M, N, Kdim);
}

// Round 2
// 258.397 us; speedup vs baseline: 1.0269x; 1.0269x over previous
//
#include <hip/hip_runtime.h>
#include <hip/hip_bf16.h>
#include <cstdint>

typedef __attribute__((ext_vector_type(8))) short short8;
typedef __attribute__((ext_vector_type(4))) float f32x4;
typedef unsigned short ushort_t;

#define S_LEN 2048
#define D_DIM 1024
#define NH 16
#define DK 64
#define BATCH 2
#define M_ROWS (BATCH * S_LEN)   // 4096

__device__ inline ushort_t f2bf(float f) {
    union { float f; uint32_t u; } v; v.f = f;
    uint32_t r = v.u + 0x7fffu + ((v.u >> 16) & 1u);  // RNE
    return (ushort_t)(r >> 16);
}

__device__ __forceinline__ void glds16(const ushort_t* g, ushort_t* l) {
    __builtin_amdgcn_global_load_lds(
        (const __attribute__((address_space(1))) uint32_t*)g,
        (__attribute__((address_space(3))) uint32_t*)l,
        16, 0, 0);
}

// ---------------- fp32 -> bf16 convert (vectorized) ----------------
__global__ void cvt_bf16(const float* __restrict__ in, ushort_t* __restrict__ out, int n4) {
    int i = blockIdx.x * blockDim.x + threadIdx.x;
    int stride = gridDim.x * blockDim.x;
    for (int idx = i; idx < n4; idx += stride) {
        float4 v = ((const float4*)in)[idx];
        ushort4 o;
        o.x = f2bf(v.x); o.y = f2bf(v.y); o.z = f2bf(v.z); o.w = f2bf(v.w);
        ((ushort4*)out)[idx] = o;
    }
}

// ---------------- GEMM: C[M,N] = A[M,K] * Bw[N,K]^T + bias[N] ----------------
// m97 structure: linear LDS, global_load_lds width=16, 2 barriers/K-step.
// MODE 0: bf16 out, layout [b,h,s,dk]   (Q, K)
// MODE 1: bf16 out, layout [b,h,dk,s]   (V transposed), packed ushort4 stores
// MODE 2: fp32 out, plain row-major [M,N] (final)
#define BM 128
#define BN 128
#define BK 32

template<int MODE>
__global__ __launch_bounds__(256) void gemm_bt(const ushort_t* __restrict__ A,
                                               const ushort_t* __restrict__ Bw,
                                               const float* __restrict__ bias,
                                               void* __restrict__ Cout,
                                               int M, int N, int K) {
    __shared__ ushort_t As[BM * BK];   // linear [128][32], row stride 64B
    __shared__ ushort_t Bs[BN * BK];
    int tid = threadIdx.x;
    int lane = tid & 63;
    int w = tid >> 6;
    int wr = w >> 1, wc = w & 1;
    int ntile = N / BN;
    int m0 = (blockIdx.x / ntile) * BM;
    int n0 = (blockIdx.x % ntile) * BN;
    int lr = lane & 15;
    int lk = (lane >> 4) * 8;

    // staging: wave w owns rows 32w..32w+31 (2 chunks of 16 rows = 1KB each)
    int srow = lane >> 2;            // 0..15 within chunk
    int scol = (lane & 3) * 8;       // element offset
    const ushort_t* aSrc0 = &A [(size_t)(m0 + w * 32      + srow) * K + scol];
    const ushort_t* aSrc1 = &A [(size_t)(m0 + w * 32 + 16 + srow) * K + scol];
    const ushort_t* bSrc0 = &Bw[(size_t)(n0 + w * 32      + srow) * K + scol];
    const ushort_t* bSrc1 = &Bw[(size_t)(n0 + w * 32 + 16 + srow) * K + scol];
    ushort_t* aDst0 = &As[(w * 32)      * BK];
    ushort_t* aDst1 = &As[(w * 32 + 16) * BK];
    ushort_t* bDst0 = &Bs[(w * 32)      * BK];
    ushort_t* bDst1 = &Bs[(w * 32 + 16) * BK];

    f32x4 acc[4][4] = {};

    for (int kt = 0; kt < K; kt += BK) {
        __syncthreads();                 // prev tile's ds_reads done
        glds16(aSrc0 + kt, aDst0);
        glds16(aSrc1 + kt, aDst1);
        glds16(bSrc0 + kt, bDst0);
        glds16(bSrc1 + kt, bDst1);
        __syncthreads();                 // vmcnt(0) drain -> tile visible

        short8 af[4], bf[4];
#pragma unroll
        for (int f = 0; f < 4; f++)
            af[f] = *(const short8*)&As[(wr * 64 + f * 16 + lr) * BK + lk];
#pragma unroll
        for (int f = 0; f < 4; f++)
            bf[f] = *(const short8*)&Bs[(wc * 64 + f * 16 + lr) * BK + lk];
#pragma unroll
        for (int i = 0; i < 4; i++)
#pragma unroll
            for (int j = 0; j < 4; j++)
                acc[i][j] = __builtin_amdgcn_mfma_f32_16x16x32_bf16(af[i], bf[j], acc[i][j], 0, 0, 0);
    }

    // epilogue: C row = m0 + wr*64 + i*16 + (lane>>4)*4 + r ; col = n0 + wc*64 + j*16 + lr
    int r0 = (lane >> 4) * 4;
#pragma unroll
    for (int j = 0; j < 4; j++) {
        int ncol = n0 + wc * 64 + j * 16 + lr;
        float bv = bias[ncol];
#pragma unroll
        for (int i = 0; i < 4; i++) {
            int mbase = m0 + wr * 64 + i * 16 + r0;
            if (MODE == 1) {
                int bb = mbase >> 11, ss = mbase & 2047;
                int hh = ncol >> 6, dk = ncol & 63;
                ushort4 pk;
                pk.x = f2bf(acc[i][j][0] + bv);
                pk.y = f2bf(acc[i][j][1] + bv);
                pk.z = f2bf(acc[i][j][2] + bv);
                pk.w = f2bf(acc[i][j][3] + bv);
                size_t idx = ((size_t)(bb * NH + hh) * DK + dk) * S_LEN + ss;
                *(ushort4*)&((ushort_t*)Cout)[idx] = pk;
            } else {
#pragma unroll
                for (int r = 0; r < 4; r++) {
                    int mm = mbase + r;
                    float v = acc[i][j][r] + bv;
                    if (MODE == 2) {
                        ((float*)Cout)[(size_t)mm * N + ncol] = v;
                    } else {
                        int bb = mm >> 11, ss = mm & 2047;
                        int hh = ncol >> 6, dk = ncol & 63;
                        size_t idx = ((size_t)(bb * NH + hh) * S_LEN + ss) * DK + dk;
                        ((ushort_t*)Cout)[idx] = f2bf(v);
                    }
                }
            }
        }
    }
}

// ---------------- Flash attention (causal) ----------------
// Q,K layout [b,h,s,dk]; Vt layout [b,h,dk,s]; out bf16 [b,s,h*dk]
// block: 256 thr (4 waves), 128 q rows (32/wave), kv tiles of 64,
// async-STAGE split: issue tile t+1 loads before computing tile t.
#define LKV 72   // 64 + 8 pad (2-way max conflict on ds_read_b128)

__global__ __launch_bounds__(256) void attn_fwd(const ushort_t* __restrict__ Q,
                                                const ushort_t* __restrict__ K,
                                                const ushort_t* __restrict__ Vt,
                                                ushort_t* __restrict__ Oa) {
    __shared__ ushort_t Ks[64][LKV];
    __shared__ ushort_t Vs[64][LKV];
    __shared__ ushort_t Ps[4][32][LKV];

    int tid = threadIdx.x;
    int lane = tid & 63;
    int w = tid >> 6;
    int qt = blockIdx.x;
    int bh = blockIdx.y;
    size_t base = (size_t)bh * S_LEN * DK;
    int q0 = qt * 128;

    int lr = lane & 15;
    int lk = (lane >> 4) * 8;
    int r0 = (lane >> 4) * 4;
    int qminw = q0 + w * 32;
    int qmaxw = qminw + 31;

    // Q fragments: 2 row-frags x 2 k-slices
    short8 qf[2][2];
#pragma unroll
    for (int qi = 0; qi < 2; qi++) {
        int qrow = qminw + qi * 16 + lr;
        qf[qi][0] = *(const short8*)&Q[base + (size_t)qrow * DK + lk];
        qf[qi][1] = *(const short8*)&Q[base + (size_t)qrow * DK + 32 + lk];
    }

    f32x4 o[4][2] = {};
    float mrow[2][4], lrow[2][4];
#pragma unroll
    for (int qi = 0; qi < 2; qi++)
#pragma unroll
        for (int i = 0; i < 4; i++) { mrow[qi][i] = -1e30f; lrow[qi][i] = 0.f; }

    int srow = tid >> 3;          // 0..31
    int scol = (tid & 7) * 8;     // 0..56

    const float LOG2E = 1.44269504f;
    const float sc = 0.125f;      // 1/sqrt(64)
    int nkv = 2 * qt + 2;

    // prologue: stage tile 0
    {
        uint4 a = *(const uint4*)&K [base + (size_t)srow * DK + scol];
        uint4 b = *(const uint4*)&K [base + (size_t)(srow + 32) * DK + scol];
        uint4 c = *(const uint4*)&Vt[base + (size_t)srow * S_LEN + scol];
        uint4 d = *(const uint4*)&Vt[base + (size_t)(srow + 32) * S_LEN + scol];
        *(uint4*)&Ks[srow][scol]      = a;
        *(uint4*)&Ks[srow + 32][scol] = b;
        *(uint4*)&Vs[srow][scol]      = c;
        *(uint4*)&Vs[srow + 32][scol] = d;
    }
    __syncthreads();

    for (int t = 0; t < nkv; ++t) {
        int kv0 = t * 64;
        int tn = (t + 1 < nkv) ? t + 1 : t;
        // issue next-tile loads early (latency hides under compute)
        uint4 kr0 = *(const uint4*)&K [base + (size_t)(tn * 64 + srow) * DK + scol];
        uint4 kr1 = *(const uint4*)&K [base + (size_t)(tn * 64 + srow + 32) * DK + scol];
        uint4 vr0 = *(const uint4*)&Vt[base + (size_t)srow * S_LEN + tn * 64 + scol];
        uint4 vr1 = *(const uint4*)&Vt[base + (size_t)(srow + 32) * S_LEN + tn * 64 + scol];

        if (kv0 <= qmaxw) {     // wave-uniform: skip fully-masked tiles
            // S = Q K^T
            f32x4 s[2][4] = {};
#pragma unroll
            for (int n = 0; n < 4; n++) {
                short8 kf0 = *(const short8*)&Ks[n * 16 + lr][lk];
                short8 kf1 = *(const short8*)&Ks[n * 16 + lr][32 + lk];
#pragma unroll
                for (int qi = 0; qi < 2; qi++) {
                    s[qi][n] = __builtin_amdgcn_mfma_f32_16x16x32_bf16(qf[qi][0], kf0, s[qi][n], 0, 0, 0);
                    s[qi][n] = __builtin_amdgcn_mfma_f32_16x16x32_bf16(qf[qi][1], kf1, s[qi][n], 0, 0, 0);
                }
            }

            if (kv0 + 63 > qminw) {   // diagonal tiles: mask
#pragma unroll
                for (int qi = 0; qi < 2; qi++)
#pragma unroll
                    for (int n = 0; n < 4; n++)
#pragma unroll
                        for (int i = 0; i < 4; i++) {
                            int qq = qminw + qi * 16 + r0 + i;
                            int kk = kv0 + n * 16 + lr;
                            s[qi][n][i] = (kk <= qq) ? s[qi][n][i] * sc : -1e30f;
                        }
            } else {
#pragma unroll
                for (int qi = 0; qi < 2; qi++)
#pragma unroll
                    for (int n = 0; n < 4; n++)
#pragma unroll
                        for (int i = 0; i < 4; i++) s[qi][n][i] *= sc;
            }

            // online softmax per q-frag
#pragma unroll
            for (int qi = 0; qi < 2; qi++) {
                float corr[4];
#pragma unroll
                for (int i = 0; i < 4; i++) {
                    float mx = fmaxf(fmaxf(s[qi][0][i], s[qi][1][i]), fmaxf(s[qi][2][i], s[qi][3][i]));
                    mx = fmaxf(mx, __shfl_xor(mx, 1));
                    mx = fmaxf(mx, __shfl_xor(mx, 2));
                    mx = fmaxf(mx, __shfl_xor(mx, 4));
                    mx = fmaxf(mx, __shfl_xor(mx, 8));
                    float mnew = fmaxf(mrow[qi][i], mx);
                    corr[i] = exp2f((mrow[qi][i] - mnew) * LOG2E);
                    mrow[qi][i] = mnew;
                }
                float psum[4] = {0.f, 0.f, 0.f, 0.f};
#pragma unroll
                for (int n = 0; n < 4; n++)
#pragma unroll
                    for (int i = 0; i < 4; i++) {
                        float p = exp2f((s[qi][n][i] - mrow[qi][i]) * LOG2E);
                        s[qi][n][i] = p;
                        psum[i] += p;
                    }
#pragma unroll
                for (int i = 0; i < 4; i++) {
                    float ps = psum[i];
                    ps += __shfl_xor(ps, 1);
                    ps += __shfl_xor(ps, 2);
                    ps += __shfl_xor(ps, 4);
                    ps += __shfl_xor(ps, 8);
                    lrow[qi][i] = lrow[qi][i] * corr[i] + ps;
                }
#pragma unroll
                for (int d = 0; d < 4; d++)
#pragma unroll
                    for (int i = 0; i < 4; i++) o[d][qi][i] *= corr[i];
                // P -> per-wave LDS (wave-internal ordering via lgkmcnt)
#pragma unroll
                for (int n = 0; n < 4; n++)
#pragma unroll
                    for (int i = 0; i < 4; i++)
                        Ps[w][qi * 16 + r0 + i][n * 16 + lr] = f2bf(s[qi][n][i]);
            }

            // O += P V
            short8 pf[2][2];
#pragma unroll
            for (int qi = 0; qi < 2; qi++)
#pragma unroll
                for (int ks = 0; ks < 2; ks++)
                    pf[qi][ks] = *(const short8*)&Ps[w][qi * 16 + lr][ks * 32 + lk];
#pragma unroll
            for (int d = 0; d < 4; d++) {
#pragma unroll
                for (int ks = 0; ks < 2; ks++) {
                    short8 vf = *(const short8*)&Vs[d * 16 + lr][ks * 32 + lk];
#pragma unroll
                    for (int qi = 0; qi < 2; qi++)
                        o[d][qi] = __builtin_amdgcn_mfma_f32_16x16x32_bf16(pf[qi][ks], vf, o[d][qi], 0, 0, 0);
                }
            }
        }

        __syncthreads();               // compute done -> safe to overwrite LDS
        if (t + 1 < nkv) {
            *(uint4*)&Ks[srow][scol]      = kr0;
            *(uint4*)&Ks[srow + 32][scol] = kr1;
            *(uint4*)&Vs[srow][scol]      = vr0;
            *(uint4*)&Vs[srow + 32][scol] = vr1;
        }
        __syncthreads();               // new tile visible
    }

    // epilogue: out[b, s, h*64+dk] bf16
    int b = bh >> 4, h = bh & 15;
#pragma unroll
    for (int d = 0; d < 4; d++)
#pragma unroll
        for (int qi = 0; qi < 2; qi++)
#pragma unroll
            for (int i = 0; i < 4; i++) {
                int qq = qminw + qi * 16 + r0 + i;
                int dk = d * 16 + lr;
                float v = o[d][qi][i] / lrow[qi][i];
                size_t idx = ((size_t)(b * S_LEN + qq)) * D_DIM + h * DK + dk;
                Oa[idx] = f2bf(v);
            }
}

// ---------------- launch ----------------
extern "C" void kernel_launch(void* const* d_in, const int* in_sizes, int n_in,
                              void* d_out, int out_size, void* d_ws, size_t ws_size,
                              hipStream_t stream) {
    const float* X  = (const float*)d_in[0];
    const float* Wq = (const float*)d_in[1];
    const float* bq = (const float*)d_in[2];
    const float* Wk = (const float*)d_in[3];
    const float* bk = (const float*)d_in[4];
    const float* Wv = (const float*)d_in[5];
    const float* bv = (const float*)d_in[6];
    const float* Wo = (const float*)d_in[7];
    const float* bo = (const float*)d_in[8];
    float* out = (float*)d_out;

    char* ws = (char*)d_ws;
    ushort_t* Xb  = (ushort_t*)ws;                          // 8 MiB [M,D] bf16
    ushort_t* Wb  = (ushort_t*)(ws + (8u  << 20));          // 2 MiB reused per weight
    ushort_t* Qb  = (ushort_t*)(ws + (10u << 20));          // 8 MiB [b,h,s,dk]
    ushort_t* Kb  = (ushort_t*)(ws + (18u << 20));          // 8 MiB [b,h,s,dk]
    ushort_t* Vtb = (ushort_t*)(ws + (26u << 20));          // 8 MiB [b,h,dk,s]
    ushort_t* Ab  = Xb;                                     // attn out reuses X slot

    const int M = M_ROWS, N = D_DIM, Kdim = D_DIM;
    dim3 cblk(256), cgrid(1024);
    int nX4 = (M * D_DIM) / 4;
    int nW4 = (D_DIM * D_DIM) / 4;
    dim3 ggrid((M / BM) * (N / BN));   // 256 blocks

    cvt_bf16<<<cgrid, cblk, 0, stream>>>(X, Xb, nX4);

    cvt_bf16<<<cgrid, cblk, 0, stream>>>(Wq, Wb, nW4);
    gemm_bt<0><<<ggrid, 256, 0, stream>>>(Xb, Wb, bq, Qb, M, N, Kdim);

    cvt_bf16<<<cgrid, cblk, 0, stream>>>(Wk, Wb, nW4);
    gemm_bt<0><<<ggrid, 256, 0, stream>>>(Xb, Wb, bk, Kb, M, N, Kdim);

    cvt_bf16<<<cgrid, cblk, 0, stream>>>(Wv, Wb, nW4);
    gemm_bt<1><<<ggrid, 256, 0, stream>>>(Xb, Wb, bv, Vtb, M, N, Kdim);

    dim3 agrid(S_LEN / 128, BATCH * NH);  // (16, 32)
    attn_fwd<<<agrid, 256, 0, stream>>>(Qb, Kb, Vtb, Ab);

    cvt_bf16<<<cgrid, cblk, 0, stream>>>(Wo, Wb, nW4);
    gemm_bt<2><<<ggrid, 256, 0, stream>>>(Ab, Wb, bo, out, M, N, Kdim);
}

// Round 3
// 151.957 us; speedup vs baseline: 1.7462x; 1.7005x over previous
//
#include <hip/hip_runtime.h>
#include <hip/hip_bf16.h>
#include <cstdint>

typedef __attribute__((ext_vector_type(8))) short short8;
typedef __attribute__((ext_vector_type(4))) float f32x4;
typedef unsigned short ushort_t;

#define S_LEN 2048
#define D_DIM 1024
#define NH 16
#define DK 64
#define BATCH 2
#define M_ROWS (BATCH * S_LEN)   // 4096
#define BK 32

__device__ inline ushort_t f2bf(float f) {
    union { float f; uint32_t u; } v; v.f = f;
    uint32_t r = v.u + 0x7fffu + ((v.u >> 16) & 1u);  // RNE
    return (ushort_t)(r >> 16);
}

__device__ __forceinline__ void glds16(const ushort_t* g, ushort_t* l) {
    __builtin_amdgcn_global_load_lds(
        (const __attribute__((address_space(1))) uint32_t*)g,
        (__attribute__((address_space(3))) uint32_t*)l,
        16, 0, 0);
}

// ---------------- fp32 -> bf16 convert (vectorized) ----------------
__global__ void cvt_bf16(const float* __restrict__ in, ushort_t* __restrict__ out, int n4) {
    int i = blockIdx.x * blockDim.x + threadIdx.x;
    int stride = gridDim.x * blockDim.x;
    for (int idx = i; idx < n4; idx += stride) {
        float4 v = ((const float4*)in)[idx];
        ushort4 o;
        o.x = f2bf(v.x); o.y = f2bf(v.y); o.z = f2bf(v.z); o.w = f2bf(v.w);
        ((ushort4*)out)[idx] = o;
    }
}

// fused convert of Wq,Wk,Wv into one [3072,1024] bf16 buffer
__global__ void cvt_w3(const float* __restrict__ wq, const float* __restrict__ wk,
                       const float* __restrict__ wv, ushort_t* __restrict__ wqkv) {
    const int seg = (D_DIM * D_DIM) / 4;   // 262144 = 2^18
    int i = blockIdx.x * blockDim.x + threadIdx.x;
    int stride = gridDim.x * blockDim.x;
    for (int idx = i; idx < 3 * seg; idx += stride) {
        int sel = idx >> 18;
        int id = idx & (seg - 1);
        const float* src = sel == 0 ? wq : (sel == 1 ? wk : wv);
        float4 v = ((const float4*)src)[id];
        ushort4 o;
        o.x = f2bf(v.x); o.y = f2bf(v.y); o.z = f2bf(v.z); o.w = f2bf(v.w);
        ((ushort4*)wqkv)[sel * seg + id] = o;
    }
}

// ---------------- GEMM: C = A[M,K] * Bw[N,K]^T + bias ----------------
// MODE 3: routed QKV epilogue (N=3072): cols 0-1023 -> Q [b,h,s,dk],
//         1024-2047 -> K [b,h,s,dk], 2048-3071 -> V^T [b,h,dk,s] packed.
// MODE 2: fp32 out, plain row-major [M,N].
template<int MODE, int BMt, int BNt>
__global__ __launch_bounds__(256) void gemm_bt(const ushort_t* __restrict__ A,
                                               const ushort_t* __restrict__ Bw,
                                               const float* __restrict__ b0,
                                               const float* __restrict__ b1,
                                               const float* __restrict__ b2,
                                               void* __restrict__ C0,
                                               void* __restrict__ C1,
                                               void* __restrict__ C2,
                                               int M, int N, int K) {
    constexpr int FM = BMt / 32, FN = BNt / 32;
    constexpr int ACH = BMt / 64, BCH = BNt / 64;
    __shared__ ushort_t As[BMt * BK];
    __shared__ ushort_t Bs[BNt * BK];
    int tid = threadIdx.x;
    int lane = tid & 63;
    int w = tid >> 6;
    int wr = w >> 1, wc = w & 1;
    int ntile = N / BNt;
    int m0 = (blockIdx.x / ntile) * BMt;
    int n0 = (blockIdx.x % ntile) * BNt;
    int lr = lane & 15;
    int lk = (lane >> 4) * 8;
    int srow = lane >> 2;            // 0..15
    int scol = (lane & 3) * 8;

    f32x4 acc[FM][FN] = {};

    for (int kt = 0; kt < K; kt += BK) {
        __syncthreads();
#pragma unroll
        for (int c = 0; c < ACH; c++)
            glds16(&A[(size_t)(m0 + w * (BMt / 4) + c * 16 + srow) * K + kt + scol],
                   &As[(w * (BMt / 4) + c * 16) * BK]);
#pragma unroll
        for (int c = 0; c < BCH; c++)
            glds16(&Bw[(size_t)(n0 + w * (BNt / 4) + c * 16 + srow) * K + kt + scol],
                   &Bs[(w * (BNt / 4) + c * 16) * BK]);
        __syncthreads();

        short8 af[FM], bf[FN];
#pragma unroll
        for (int f = 0; f < FM; f++)
            af[f] = *(const short8*)&As[(wr * (BMt / 2) + f * 16 + lr) * BK + lk];
#pragma unroll
        for (int f = 0; f < FN; f++)
            bf[f] = *(const short8*)&Bs[(wc * (BNt / 2) + f * 16 + lr) * BK + lk];
#pragma unroll
        for (int i = 0; i < FM; i++)
#pragma unroll
            for (int j = 0; j < FN; j++)
                acc[i][j] = __builtin_amdgcn_mfma_f32_16x16x32_bf16(af[i], bf[j], acc[i][j], 0, 0, 0);
    }

    int r0 = (lane >> 4) * 4;
#pragma unroll
    for (int j = 0; j < FN; j++) {
        int ncol = n0 + wc * (BNt / 2) + j * 16 + lr;
        if (MODE == 2) {
            float bv = b0[ncol];
#pragma unroll
            for (int i = 0; i < FM; i++) {
                int mbase = m0 + wr * (BMt / 2) + i * 16 + r0;
#pragma unroll
                for (int r = 0; r < 4; r++)
                    ((float*)C0)[(size_t)(mbase + r) * N + ncol] = acc[i][j][r] + bv;
            }
        } else {
            int sel = n0 >> 10;                    // block-uniform
            const float* bp = sel == 0 ? b0 : (sel == 1 ? b1 : b2);
            int nc = ncol & 1023;
            float bv = bp[nc];
            int hh = nc >> 6, dk = nc & 63;
            ushort_t* Co = (ushort_t*)(sel == 0 ? C0 : (sel == 1 ? C1 : C2));
#pragma unroll
            for (int i = 0; i < FM; i++) {
                int mbase = m0 + wr * (BMt / 2) + i * 16 + r0;
                int bb = mbase >> 11, ss = mbase & 2047;
                if (sel == 2) {
                    ushort4 pk;
                    pk.x = f2bf(acc[i][j][0] + bv);
                    pk.y = f2bf(acc[i][j][1] + bv);
                    pk.z = f2bf(acc[i][j][2] + bv);
                    pk.w = f2bf(acc[i][j][3] + bv);
                    size_t idx = ((size_t)(bb * NH + hh) * DK + dk) * S_LEN + ss;
                    *(ushort4*)&Co[idx] = pk;
                } else {
#pragma unroll
                    for (int r = 0; r < 4; r++) {
                        size_t idx = ((size_t)(bb * NH + hh) * S_LEN + (ss + r)) * DK + dk;
                        Co[idx] = f2bf(acc[i][j][r] + bv);
                    }
                }
            }
        }
    }
}

// ---------------- Flash attention (causal, work-balanced pairs) ----------------
// Block j processes 64-row q-tiles {j, 31-j} in one merged kv loop: uniform
// 33 tile-compute-units/block. Swapped QK^T (mfma(K,Q)) -> per-lane softmax.
// Double-buffered K/V, one barrier per kv tile.
#define LKV 72

__global__ __launch_bounds__(256) void attn_fwd(const ushort_t* __restrict__ Q,
                                                const ushort_t* __restrict__ K,
                                                const ushort_t* __restrict__ Vt,
                                                ushort_t* __restrict__ Oa) {
    __shared__ ushort_t Ks[2][64][LKV];
    __shared__ ushort_t Vs[2][64][LKV];
    __shared__ ushort_t Ps[4][32][LKV];

    int tid = threadIdx.x;
    int lane = tid & 63;
    int w = tid >> 6;
    int jb = blockIdx.x;           // 0..15
    int bh = blockIdx.y;
    size_t base = (size_t)bh * S_LEN * DK;

    int lr = lane & 15;
    int lk = (lane >> 4) * 8;
    int r0 = (lane >> 4) * 4;

    int qbase[2];
    qbase[0] = jb * 64 + w * 16;            // lower tile (j)
    qbase[1] = (31 - jb) * 64 + w * 16;     // upper tile (31-j)
    int NT = 32 - jb;                        // kv tiles for upper

    short8 qf[2][2];
#pragma unroll
    for (int qi = 0; qi < 2; qi++) {
        int qrow = qbase[qi] + lr;
        qf[qi][0] = *(const short8*)&Q[base + (size_t)qrow * DK + lk];
        qf[qi][1] = *(const short8*)&Q[base + (size_t)qrow * DK + 32 + lk];
    }

    f32x4 o[4][2] = {};
    float mrow[2] = {-1e30f, -1e30f};
    float lrow[2] = {0.f, 0.f};

    int srow = tid >> 3;          // 0..31
    int scol = (tid & 7) * 8;

    const float LOG2E = 1.44269504f;
    const float sc = 0.125f;      // 1/sqrt(64)

    // prologue: stage tile 0 into buf 0
    *(uint4*)&Ks[0][srow][scol]      = *(const uint4*)&K[base + (size_t)srow * DK + scol];
    *(uint4*)&Ks[0][srow + 32][scol] = *(const uint4*)&K[base + (size_t)(srow + 32) * DK + scol];
    *(uint4*)&Vs[0][srow][scol]      = *(const uint4*)&Vt[base + (size_t)srow * S_LEN + scol];
    *(uint4*)&Vs[0][srow + 32][scol] = *(const uint4*)&Vt[base + (size_t)(srow + 32) * S_LEN + scol];
    __syncthreads();

    int cur = 0;
    for (int t = 0; t < NT; ++t) {
        int kv0 = t * 64;
        bool last = (t == NT - 1);
        uint4 kr0, kr1, vr0, vr1;
        if (!last) {
            int tn = t + 1;
            kr0 = *(const uint4*)&K [base + (size_t)(tn * 64 + srow) * DK + scol];
            kr1 = *(const uint4*)&K [base + (size_t)(tn * 64 + srow + 32) * DK + scol];
            vr0 = *(const uint4*)&Vt[base + (size_t)srow * S_LEN + tn * 64 + scol];
            vr1 = *(const uint4*)&Vt[base + (size_t)(srow + 32) * S_LEN + tn * 64 + scol];
        }
        bool act0 = (t <= jb);

        // swapped QK^T: st rows = kv, cols = q
        f32x4 st[2][4] = {};
#pragma unroll
        for (int n = 0; n < 4; n++) {
            short8 kf0 = *(const short8*)&Ks[cur][n * 16 + lr][lk];
            short8 kf1 = *(const short8*)&Ks[cur][n * 16 + lr][32 + lk];
            st[1][n] = __builtin_amdgcn_mfma_f32_16x16x32_bf16(kf0, qf[1][0], st[1][n], 0, 0, 0);
            st[1][n] = __builtin_amdgcn_mfma_f32_16x16x32_bf16(kf1, qf[1][1], st[1][n], 0, 0, 0);
            if (act0) {
                st[0][n] = __builtin_amdgcn_mfma_f32_16x16x32_bf16(kf0, qf[0][0], st[0][n], 0, 0, 0);
                st[0][n] = __builtin_amdgcn_mfma_f32_16x16x32_bf16(kf1, qf[0][1], st[0][n], 0, 0, 0);
            }
        }

#pragma unroll
        for (int qi = 0; qi < 2; qi++) {
            if (qi == 0 && !act0) continue;
            int qcol = qbase[qi] + lr;          // this lane's q row
            if (kv0 + 63 > qbase[qi]) {         // diagonal: mask
#pragma unroll
                for (int n = 0; n < 4; n++)
#pragma unroll
                    for (int i = 0; i < 4; i++) {
                        int kvg = kv0 + n * 16 + r0 + i;
                        st[qi][n][i] = (kvg <= qcol) ? st[qi][n][i] * sc : -1e30f;
                    }
            } else {
#pragma unroll
                for (int n = 0; n < 4; n++)
#pragma unroll
                    for (int i = 0; i < 4; i++) st[qi][n][i] *= sc;
            }
            // in-lane max over 16, then 2 shfl across groups
            float m01 = fmaxf(fmaxf(st[qi][0][0], st[qi][0][1]), fmaxf(st[qi][0][2], st[qi][0][3]));
            float m11 = fmaxf(fmaxf(st[qi][1][0], st[qi][1][1]), fmaxf(st[qi][1][2], st[qi][1][3]));
            float m21 = fmaxf(fmaxf(st[qi][2][0], st[qi][2][1]), fmaxf(st[qi][2][2], st[qi][2][3]));
            float m31 = fmaxf(fmaxf(st[qi][3][0], st[qi][3][1]), fmaxf(st[qi][3][2], st[qi][3][3]));
            float mx = fmaxf(fmaxf(m01, m11), fmaxf(m21, m31));
            mx = fmaxf(mx, __shfl_xor(mx, 16));
            mx = fmaxf(mx, __shfl_xor(mx, 32));
            float mnew = fmaxf(mrow[qi], mx);
            float corr = exp2f((mrow[qi] - mnew) * LOG2E);
            mrow[qi] = mnew;
            float psum = 0.f;
#pragma unroll
            for (int n = 0; n < 4; n++)
#pragma unroll
                for (int i = 0; i < 4; i++) {
                    float p = exp2f((st[qi][n][i] - mnew) * LOG2E);
                    st[qi][n][i] = p;
                    psum += p;
                }
            psum += __shfl_xor(psum, 16);
            psum += __shfl_xor(psum, 32);
            lrow[qi] = lrow[qi] * corr + psum;
            float cb[4];
#pragma unroll
            for (int i = 0; i < 4; i++) cb[i] = __shfl(corr, r0 + i);
#pragma unroll
            for (int d = 0; d < 4; d++)
#pragma unroll
                for (int i = 0; i < 4; i++) o[d][qi][i] *= cb[i];
            // P[q][kv] packed write: 4x ds_write_b64
#pragma unroll
            for (int n = 0; n < 4; n++) {
                ushort4 pk;
                pk.x = f2bf(st[qi][n][0]);
                pk.y = f2bf(st[qi][n][1]);
                pk.z = f2bf(st[qi][n][2]);
                pk.w = f2bf(st[qi][n][3]);
                *(ushort4*)&Ps[w][qi * 16 + lr][n * 16 + r0] = pk;
            }
        }

        // PV
        short8 pf1[2], pf0[2];
#pragma unroll
        for (int ks = 0; ks < 2; ks++)
            pf1[ks] = *(const short8*)&Ps[w][16 + lr][ks * 32 + lk];
        if (act0)
#pragma unroll
            for (int ks = 0; ks < 2; ks++)
                pf0[ks] = *(const short8*)&Ps[w][lr][ks * 32 + lk];
#pragma unroll
        for (int d = 0; d < 4; d++)
#pragma unroll
            for (int ks = 0; ks < 2; ks++) {
                short8 vf = *(const short8*)&Vs[cur][d * 16 + lr][ks * 32 + lk];
                o[d][1] = __builtin_amdgcn_mfma_f32_16x16x32_bf16(pf1[ks], vf, o[d][1], 0, 0, 0);
                if (act0)
                    o[d][0] = __builtin_amdgcn_mfma_f32_16x16x32_bf16(pf0[ks], vf, o[d][0], 0, 0, 0);
            }

        if (!last) {
            *(uint4*)&Ks[cur ^ 1][srow][scol]      = kr0;
            *(uint4*)&Ks[cur ^ 1][srow + 32][scol] = kr1;
            *(uint4*)&Vs[cur ^ 1][srow][scol]      = vr0;
            *(uint4*)&Vs[cur ^ 1][srow + 32][scol] = vr1;
        }
        __syncthreads();
        cur ^= 1;
    }

    // epilogue
    int b = bh >> 4, h = bh & 15;
#pragma unroll
    for (int qi = 0; qi < 2; qi++) {
        float lb[4];
#pragma unroll
        for (int i = 0; i < 4; i++) lb[i] = __shfl(lrow[qi], r0 + i);
#pragma unroll
        for (int d = 0; d < 4; d++)
#pragma unroll
            for (int i = 0; i < 4; i++) {
                int qq = qbase[qi] + r0 + i;
                int dk = d * 16 + lr;
                size_t idx = ((size_t)(b * S_LEN + qq)) * D_DIM + h * DK + dk;
                Oa[idx] = f2bf(o[d][qi][i] / lb[i]);
            }
    }
}

// ---------------- launch ----------------
extern "C" void kernel_launch(void* const* d_in, const int* in_sizes, int n_in,
                              void* d_out, int out_size, void* d_ws, size_t ws_size,
                              hipStream_t stream) {
    const float* X  = (const float*)d_in[0];
    const float* Wq = (const float*)d_in[1];
    const float* bq = (const float*)d_in[2];
    const float* Wk = (const float*)d_in[3];
    const float* bk = (const float*)d_in[4];
    const float* Wv = (const float*)d_in[5];
    const float* bv = (const float*)d_in[6];
    const float* Wo = (const float*)d_in[7];
    const float* bo = (const float*)d_in[8];
    float* out = (float*)d_out;

    char* ws = (char*)d_ws;
    ushort_t* Xb    = (ushort_t*)ws;                        // 8 MiB [M,D] bf16 (later: attn out)
    ushort_t* Wqkvb = (ushort_t*)(ws + (8u  << 20));        // 6 MiB [3072,1024]; later Wo reuses
    ushort_t* Qb    = (ushort_t*)(ws + (14u << 20));        // 8 MiB [b,h,s,dk]
    ushort_t* Kb    = (ushort_t*)(ws + (22u << 20));        // 8 MiB [b,h,s,dk]
    ushort_t* Vtb   = (ushort_t*)(ws + (30u << 20));        // 8 MiB [b,h,dk,s]
    ushort_t* Wob   = Wqkvb;                                // reuse after QKV gemm
    ushort_t* Ab    = Xb;                                   // attn out reuses X slot

    const int M = M_ROWS;
    int nX4 = (M * D_DIM) / 4;          // 1048576
    int nW4 = (D_DIM * D_DIM) / 4;      // 262144

    cvt_bf16<<<2048, 256, 0, stream>>>(X, Xb, nX4);
    cvt_w3<<<2048, 256, 0, stream>>>(Wq, Wk, Wv, Wqkvb);

    // fused QKV: 32 x 24 = 768 blocks (3/CU)
    gemm_bt<3, 128, 128><<<dim3((M / 128) * (3072 / 128)), 256, 0, stream>>>(
        Xb, Wqkvb, bq, bk, bv, Qb, Kb, Vtb, M, 3072, D_DIM);

    cvt_bf16<<<2048, 256, 0, stream>>>(Wo, Wob, nW4);   // safe: after QKV gemm in stream order

    dim3 agrid(16, BATCH * NH);   // 512 blocks, 2/CU
    attn_fwd<<<agrid, 256, 0, stream>>>(Qb, Kb, Vtb, Ab);

    // Wo gemm: 64x128 tiles -> 64 x 8 = 512 blocks (2/CU)
    gemm_bt<2, 64, 128><<<dim3((M / 64) * (D_DIM / 128)), 256, 0, stream>>>(
        Ab, Wob, bo, bo, bo, out, out, out, M, D_DIM, D_DIM);
}

// Round 4
// 137.959 us; speedup vs baseline: 1.9234x; 1.1015x over previous
//
#include <hip/hip_runtime.h>
#include <hip/hip_bf16.h>
#include <cstdint>

typedef __attribute__((ext_vector_type(8))) short short8;
typedef __attribute__((ext_vector_type(4))) float f32x4;
typedef __attribute__((ext_vector_type(2))) unsigned int uint2v;
typedef unsigned short ushort_t;

#define S_LEN 2048
#define D_DIM 1024
#define NH 16
#define DK 64
#define BATCH 2
#define M_ROWS (BATCH * S_LEN)   // 4096
#define BK 32

__device__ inline ushort_t f2bf(float f) {
    union { float f; uint32_t u; } v; v.f = f;
    uint32_t r = v.u + 0x7fffu + ((v.u >> 16) & 1u);  // RNE
    return (ushort_t)(r >> 16);
}

__device__ __forceinline__ ushort_t bfc(float f) {
    __hip_bfloat16 h = __float2bfloat16(f);          // HW v_cvt_pk path (m240)
    return __builtin_bit_cast(ushort_t, h);
}

__device__ __forceinline__ void glds16(const ushort_t* g, ushort_t* l) {
    __builtin_amdgcn_global_load_lds(
        (const __attribute__((address_space(1))) uint32_t*)g,
        (__attribute__((address_space(3))) uint32_t*)l,
        16, 0, 0);
}

// cross-lane reduce over the 4 16-lane groups (lanes l, l^16, l^32, l^48)
__device__ __forceinline__ float red_max4(float x) {
#if __has_builtin(__builtin_amdgcn_permlane16_swap) && __has_builtin(__builtin_amdgcn_permlane32_swap)
    uint2v a = __builtin_amdgcn_permlane16_swap(__float_as_uint(x), __float_as_uint(x), false, false);
    float y = fmaxf(__uint_as_float(a.x), __uint_as_float(a.y));
    uint2v b = __builtin_amdgcn_permlane32_swap(__float_as_uint(y), __float_as_uint(y), false, false);
    return fmaxf(__uint_as_float(b.x), __uint_as_float(b.y));
#else
    x = fmaxf(x, __shfl_xor(x, 16));
    return fmaxf(x, __shfl_xor(x, 32));
#endif
}
__device__ __forceinline__ float red_sum4(float x) {
#if __has_builtin(__builtin_amdgcn_permlane16_swap) && __has_builtin(__builtin_amdgcn_permlane32_swap)
    uint2v a = __builtin_amdgcn_permlane16_swap(__float_as_uint(x), __float_as_uint(x), false, false);
    float y = __uint_as_float(a.x) + __uint_as_float(a.y);
    uint2v b = __builtin_amdgcn_permlane32_swap(__float_as_uint(y), __float_as_uint(y), false, false);
    return __uint_as_float(b.x) + __uint_as_float(b.y);
#else
    x += __shfl_xor(x, 16);
    return x + __shfl_xor(x, 32);
#endif
}

// ---------------- fp32 -> bf16 convert (vectorized) ----------------
__global__ void cvt_bf16(const float* __restrict__ in, ushort_t* __restrict__ out, int n4) {
    int i = blockIdx.x * blockDim.x + threadIdx.x;
    int stride = gridDim.x * blockDim.x;
    for (int idx = i; idx < n4; idx += stride) {
        float4 v = ((const float4*)in)[idx];
        ushort4 o;
        o.x = f2bf(v.x); o.y = f2bf(v.y); o.z = f2bf(v.z); o.w = f2bf(v.w);
        ((ushort4*)out)[idx] = o;
    }
}

// fused convert of Wq,Wk,Wv into one [3072,1024] bf16 buffer
__global__ void cvt_w3(const float* __restrict__ wq, const float* __restrict__ wk,
                       const float* __restrict__ wv, ushort_t* __restrict__ wqkv) {
    const int seg = (D_DIM * D_DIM) / 4;   // 262144 = 2^18
    int i = blockIdx.x * blockDim.x + threadIdx.x;
    int stride = gridDim.x * blockDim.x;
    for (int idx = i; idx < 3 * seg; idx += stride) {
        int sel = idx >> 18;
        int id = idx & (seg - 1);
        const float* src = sel == 0 ? wq : (sel == 1 ? wk : wv);
        float4 v = ((const float4*)src)[id];
        ushort4 o;
        o.x = f2bf(v.x); o.y = f2bf(v.y); o.z = f2bf(v.z); o.w = f2bf(v.w);
        ((ushort4*)wqkv)[sel * seg + id] = o;
    }
}

// ---------------- GEMM: C = A[M,K] * Bw[N,K]^T + bias ----------------
template<int MODE, int BMt, int BNt>
__global__ __launch_bounds__(256) void gemm_bt(const ushort_t* __restrict__ A,
                                               const ushort_t* __restrict__ Bw,
                                               const float* __restrict__ b0,
                                               const float* __restrict__ b1,
                                               const float* __restrict__ b2,
                                               void* __restrict__ C0,
                                               void* __restrict__ C1,
                                               void* __restrict__ C2,
                                               int M, int N, int K) {
    constexpr int FM = BMt / 32, FN = BNt / 32;
    constexpr int ACH = BMt / 64, BCH = BNt / 64;
    __shared__ ushort_t As[BMt * BK];
    __shared__ ushort_t Bs[BNt * BK];
    int tid = threadIdx.x;
    int lane = tid & 63;
    int w = tid >> 6;
    int wr = w >> 1, wc = w & 1;
    int ntile = N / BNt;
    int m0 = (blockIdx.x / ntile) * BMt;
    int n0 = (blockIdx.x % ntile) * BNt;
    int lr = lane & 15;
    int lk = (lane >> 4) * 8;
    int srow = lane >> 2;            // 0..15
    int scol = (lane & 3) * 8;

    f32x4 acc[FM][FN] = {};

    for (int kt = 0; kt < K; kt += BK) {
        __syncthreads();
#pragma unroll
        for (int c = 0; c < ACH; c++)
            glds16(&A[(size_t)(m0 + w * (BMt / 4) + c * 16 + srow) * K + kt + scol],
                   &As[(w * (BMt / 4) + c * 16) * BK]);
#pragma unroll
        for (int c = 0; c < BCH; c++)
            glds16(&Bw[(size_t)(n0 + w * (BNt / 4) + c * 16 + srow) * K + kt + scol],
                   &Bs[(w * (BNt / 4) + c * 16) * BK]);
        __syncthreads();

        short8 af[FM], bf[FN];
#pragma unroll
        for (int f = 0; f < FM; f++)
            af[f] = *(const short8*)&As[(wr * (BMt / 2) + f * 16 + lr) * BK + lk];
#pragma unroll
        for (int f = 0; f < FN; f++)
            bf[f] = *(const short8*)&Bs[(wc * (BNt / 2) + f * 16 + lr) * BK + lk];
#pragma unroll
        for (int i = 0; i < FM; i++)
#pragma unroll
            for (int j = 0; j < FN; j++)
                acc[i][j] = __builtin_amdgcn_mfma_f32_16x16x32_bf16(af[i], bf[j], acc[i][j], 0, 0, 0);
    }

    int r0 = (lane >> 4) * 4;
#pragma unroll
    for (int j = 0; j < FN; j++) {
        int ncol = n0 + wc * (BNt / 2) + j * 16 + lr;
        if (MODE == 2) {
            float bv = b0[ncol];
#pragma unroll
            for (int i = 0; i < FM; i++) {
                int mbase = m0 + wr * (BMt / 2) + i * 16 + r0;
#pragma unroll
                for (int r = 0; r < 4; r++)
                    ((float*)C0)[(size_t)(mbase + r) * N + ncol] = acc[i][j][r] + bv;
            }
        } else {
            int sel = n0 >> 10;                    // block-uniform
            const float* bp = sel == 0 ? b0 : (sel == 1 ? b1 : b2);
            int nc = ncol & 1023;
            float bv = bp[nc];
            int hh = nc >> 6, dk = nc & 63;
            ushort_t* Co = (ushort_t*)(sel == 0 ? C0 : (sel == 1 ? C1 : C2));
#pragma unroll
            for (int i = 0; i < FM; i++) {
                int mbase = m0 + wr * (BMt / 2) + i * 16 + r0;
                int bb = mbase >> 11, ss = mbase & 2047;
                if (sel == 2) {
                    ushort4 pk;
                    pk.x = f2bf(acc[i][j][0] + bv);
                    pk.y = f2bf(acc[i][j][1] + bv);
                    pk.z = f2bf(acc[i][j][2] + bv);
                    pk.w = f2bf(acc[i][j][3] + bv);
                    size_t idx = ((size_t)(bb * NH + hh) * DK + dk) * S_LEN + ss;
                    *(ushort4*)&Co[idx] = pk;
                } else {
#pragma unroll
                    for (int r = 0; r < 4; r++) {
                        size_t idx = ((size_t)(bb * NH + hh) * S_LEN + (ss + r)) * DK + dk;
                        Co[idx] = f2bf(acc[i][j][r] + bv);
                    }
                }
            }
        }
    }
}

// ---------------- Flash attention (causal, work-balanced pairs) ----------------
// Grid (bh, jb) = (32,16): bh-major => blocks sharing (b,h) map to the same
// XCD mod-8 class (K/V L2 locality). Block jb does q-tiles {jb, 31-jb}.
// K/V: [2][64][64] XOR-swizzled (no pad), reg-staged dbuf. P: per-wave padded.
// Softmax: permlane reduces, fused scale*log2e FMA, defer-max (THR=8).
#define CSC 0.1803368801f   // 0.125 * log2(e)

__global__ __launch_bounds__(256) void attn_fwd(const ushort_t* __restrict__ Q,
                                                const ushort_t* __restrict__ K,
                                                const ushort_t* __restrict__ Vt,
                                                ushort_t* __restrict__ Oa) {
    __shared__ ushort_t Ks[2][64 * 64];
    __shared__ ushort_t Vs[2][64 * 64];
    __shared__ ushort_t Ps[4][32][72];

    int tid = threadIdx.x;
    int lane = tid & 63;
    int w = tid >> 6;
    int bh = blockIdx.x;           // 0..31
    int jb = blockIdx.y;           // 0..15
    size_t base = (size_t)bh * S_LEN * DK;

    int lr = lane & 15;
    int lk = (lane >> 4) * 8;
    int g16 = (lane >> 4) * 16;    // byte col of fragment slice
    int r0 = (lane >> 4) * 4;

    // XOR swizzle: ushort index for (row, byte-col) in a [64][128B] tile
    auto swz = [](int row, int cb) { return (row * 128 + (cb ^ ((row & 7) << 4))) >> 1; };

    int qbase[2];
    qbase[0] = jb * 64 + w * 16;            // lower tile (jb)
    qbase[1] = (31 - jb) * 64 + w * 16;     // upper tile (31-jb)
    int NT = 32 - jb;

    short8 qf[2][2];
#pragma unroll
    for (int qi = 0; qi < 2; qi++) {
        int qrow = qbase[qi] + lr;
        qf[qi][0] = *(const short8*)&Q[base + (size_t)qrow * DK + lk];
        qf[qi][1] = *(const short8*)&Q[base + (size_t)qrow * DK + 32 + lk];
    }

    f32x4 o[4][2] = {};
    float mrowL[2] = {-1e30f, -1e30f};   // running max in sc*log2e domain
    float lrow[2] = {0.f, 0.f};

    int sr = tid >> 3;            // 0..31
    int scb = (tid & 7) * 16;     // byte col
    int sce = (tid & 7) * 8;      // element col

    // prologue: stage tile 0 into buf 0 (swizzled)
    *(uint4*)&Ks[0][swz(sr, scb)]      = *(const uint4*)&K [base + (size_t)sr * DK + sce];
    *(uint4*)&Ks[0][swz(sr + 32, scb)] = *(const uint4*)&K [base + (size_t)(sr + 32) * DK + sce];
    *(uint4*)&Vs[0][swz(sr, scb)]      = *(const uint4*)&Vt[base + (size_t)sr * S_LEN + sce];
    *(uint4*)&Vs[0][swz(sr + 32, scb)] = *(const uint4*)&Vt[base + (size_t)(sr + 32) * S_LEN + sce];
    __syncthreads();

    int cur = 0;
    for (int t = 0; t < NT; ++t) {
        int kv0 = t * 64;
        bool last = (t == NT - 1);
        uint4 kr0, kr1, vr0, vr1;
        if (!last) {
            int tn = t + 1;
            kr0 = *(const uint4*)&K [base + (size_t)(tn * 64 + sr) * DK + sce];
            kr1 = *(const uint4*)&K [base + (size_t)(tn * 64 + sr + 32) * DK + sce];
            vr0 = *(const uint4*)&Vt[base + (size_t)sr * S_LEN + tn * 64 + sce];
            vr1 = *(const uint4*)&Vt[base + (size_t)(sr + 32) * S_LEN + tn * 64 + sce];
        }
        bool act0 = (t <= jb);

        // swapped QK^T: st rows = kv (regs), cols = q (lanes)
        f32x4 st[2][4] = {};
        __builtin_amdgcn_s_setprio(1);
#pragma unroll
        for (int n = 0; n < 4; n++) {
            short8 kf0 = *(const short8*)&Ks[cur][swz(n * 16 + lr, g16)];
            short8 kf1 = *(const short8*)&Ks[cur][swz(n * 16 + lr, 64 + g16)];
            st[1][n] = __builtin_amdgcn_mfma_f32_16x16x32_bf16(kf0, qf[1][0], st[1][n], 0, 0, 0);
            st[1][n] = __builtin_amdgcn_mfma_f32_16x16x32_bf16(kf1, qf[1][1], st[1][n], 0, 0, 0);
            if (act0) {
                st[0][n] = __builtin_amdgcn_mfma_f32_16x16x32_bf16(kf0, qf[0][0], st[0][n], 0, 0, 0);
                st[0][n] = __builtin_amdgcn_mfma_f32_16x16x32_bf16(kf1, qf[0][1], st[0][n], 0, 0, 0);
            }
        }
        __builtin_amdgcn_s_setprio(0);

#pragma unroll
        for (int qi = 0; qi < 2; qi++) {
            if (qi == 0 && !act0) continue;
            int qcol = qbase[qi] + lr;          // this lane's q row
            if (kv0 + 63 > qbase[qi]) {         // diagonal: mask (raw domain)
#pragma unroll
                for (int n = 0; n < 4; n++)
#pragma unroll
                    for (int i = 0; i < 4; i++) {
                        int kvg = kv0 + n * 16 + r0 + i;
                        if (kvg > qcol) st[qi][n][i] = -1e30f;
                    }
            }
            // raw max tree then one scale
            float mx = fmaxf(
                fmaxf(fmaxf(fmaxf(st[qi][0][0], st[qi][0][1]), fmaxf(st[qi][0][2], st[qi][0][3])),
                      fmaxf(fmaxf(st[qi][1][0], st[qi][1][1]), fmaxf(st[qi][1][2], st[qi][1][3]))),
                fmaxf(fmaxf(fmaxf(st[qi][2][0], st[qi][2][1]), fmaxf(st[qi][2][2], st[qi][2][3])),
                      fmaxf(fmaxf(st[qi][3][0], st[qi][3][1]), fmaxf(st[qi][3][2], st[qi][3][3]))));
            float mxL = red_max4(mx) * CSC;

            bool skip = __all(mxL <= mrowL[qi] + 8.0f);   // T13 defer-max
            float corr = 1.0f;
            float mnewL = mrowL[qi];
            if (!skip) {
                mnewL = fmaxf(mrowL[qi], mxL);
                corr = exp2f(mrowL[qi] - mnewL);
                mrowL[qi] = mnewL;
            }

            float psum = 0.f;
#pragma unroll
            for (int n = 0; n < 4; n++) {
                ushort4 pk;
#pragma unroll
                for (int i = 0; i < 4; i++) {
                    float p = exp2f(fmaf(st[qi][n][i], CSC, -mnewL));
                    st[qi][n][i] = p;
                    psum += p;
                }
                pk.x = bfc(st[qi][n][0]);
                pk.y = bfc(st[qi][n][1]);
                pk.z = bfc(st[qi][n][2]);
                pk.w = bfc(st[qi][n][3]);
                *(ushort4*)&Ps[w][qi * 16 + lr][n * 16 + r0] = pk;
            }
            psum = red_sum4(psum);

            if (skip) {
                lrow[qi] += psum;
            } else {
                lrow[qi] = lrow[qi] * corr + psum;
                float cb[4];
#pragma unroll
                for (int i = 0; i < 4; i++) cb[i] = __shfl(corr, r0 + i);
#pragma unroll
                for (int d = 0; d < 4; d++)
#pragma unroll
                    for (int i = 0; i < 4; i++) o[d][qi][i] *= cb[i];
            }
        }

        // PV
        short8 pf1[2], pf0[2];
#pragma unroll
        for (int ks = 0; ks < 2; ks++)
            pf1[ks] = *(const short8*)&Ps[w][16 + lr][ks * 32 + lk];
        if (act0)
#pragma unroll
            for (int ks = 0; ks < 2; ks++)
                pf0[ks] = *(const short8*)&Ps[w][lr][ks * 32 + lk];
        __builtin_amdgcn_s_setprio(1);
#pragma unroll
        for (int d = 0; d < 4; d++)
#pragma unroll
            for (int ks = 0; ks < 2; ks++) {
                short8 vf = *(const short8*)&Vs[cur][swz(d * 16 + lr, ks * 64 + g16)];
                o[d][1] = __builtin_amdgcn_mfma_f32_16x16x32_bf16(pf1[ks], vf, o[d][1], 0, 0, 0);
                if (act0)
                    o[d][0] = __builtin_amdgcn_mfma_f32_16x16x32_bf16(pf0[ks], vf, o[d][0], 0, 0, 0);
            }
        __builtin_amdgcn_s_setprio(0);

        if (!last) {
            *(uint4*)&Ks[cur ^ 1][swz(sr, scb)]      = kr0;
            *(uint4*)&Ks[cur ^ 1][swz(sr + 32, scb)] = kr1;
            *(uint4*)&Vs[cur ^ 1][swz(sr, scb)]      = vr0;
            *(uint4*)&Vs[cur ^ 1][swz(sr + 32, scb)] = vr1;
        }
        __syncthreads();
        cur ^= 1;
    }

    // epilogue
    int b = bh >> 4, h = bh & 15;
#pragma unroll
    for (int qi = 0; qi < 2; qi++) {
        float lb[4];
#pragma unroll
        for (int i = 0; i < 4; i++) lb[i] = __shfl(lrow[qi], r0 + i);
#pragma unroll
        for (int d = 0; d < 4; d++)
#pragma unroll
            for (int i = 0; i < 4; i++) {
                int qq = qbase[qi] + r0 + i;
                int dk = d * 16 + lr;
                size_t idx = ((size_t)(b * S_LEN + qq)) * D_DIM + h * DK + dk;
                Oa[idx] = bfc(o[d][qi][i] / lb[i]);
            }
    }
}

// ---------------- launch ----------------
extern "C" void kernel_launch(void* const* d_in, const int* in_sizes, int n_in,
                              void* d_out, int out_size, void* d_ws, size_t ws_size,
                              hipStream_t stream) {
    const float* X  = (const float*)d_in[0];
    const float* Wq = (const float*)d_in[1];
    const float* bq = (const float*)d_in[2];
    const float* Wk = (const float*)d_in[3];
    const float* bk = (const float*)d_in[4];
    const float* Wv = (const float*)d_in[5];
    const float* bv = (const float*)d_in[6];
    const float* Wo = (const float*)d_in[7];
    const float* bo = (const float*)d_in[8];
    float* out = (float*)d_out;

    char* ws = (char*)d_ws;
    ushort_t* Xb    = (ushort_t*)ws;                        // 8 MiB [M,D] bf16 (later: attn out)
    ushort_t* Wqkvb = (ushort_t*)(ws + (8u  << 20));        // 6 MiB [3072,1024]; later Wo reuses
    ushort_t* Qb    = (ushort_t*)(ws + (14u << 20));        // 8 MiB [b,h,s,dk]
    ushort_t* Kb    = (ushort_t*)(ws + (22u << 20));        // 8 MiB [b,h,s,dk]
    ushort_t* Vtb   = (ushort_t*)(ws + (30u << 20));        // 8 MiB [b,h,dk,s]
    ushort_t* Wob   = Wqkvb;                                // reuse after QKV gemm
    ushort_t* Ab    = Xb;                                   // attn out reuses X slot

    const int M = M_ROWS;
    int nX4 = (M * D_DIM) / 4;
    int nW4 = (D_DIM * D_DIM) / 4;

    cvt_bf16<<<2048, 256, 0, stream>>>(X, Xb, nX4);
    cvt_w3<<<2048, 256, 0, stream>>>(Wq, Wk, Wv, Wqkvb);

    // fused QKV: 32 x 24 = 768 blocks (3/CU)
    gemm_bt<3, 128, 128><<<dim3((M / 128) * (3072 / 128)), 256, 0, stream>>>(
        Xb, Wqkvb, bq, bk, bv, Qb, Kb, Vtb, M, 3072, D_DIM);

    cvt_bf16<<<2048, 256, 0, stream>>>(Wo, Wob, nW4);

    dim3 agrid(BATCH * NH, 16);   // bh-major: same-bh blocks share an XCD class
    attn_fwd<<<agrid, 256, 0, stream>>>(Qb, Kb, Vtb, Ab);

    // Wo gemm: 64x128 tiles -> 512 blocks (2/CU)
    gemm_bt<2, 64, 128><<<dim3((M / 64) * (D_DIM / 128)), 256, 0, stream>>>(
        Ab, Wob, bo, bo, bo, out, out, out, M, D_DIM, D_DIM);
}

// Round 5
// 134.977 us; speedup vs baseline: 1.9659x; 1.0221x over previous
//
#include <hip/hip_runtime.h>
#include <hip/hip_bf16.h>
#include <cstdint>

typedef __attribute__((ext_vector_type(8))) short short8;
typedef __attribute__((ext_vector_type(4))) float f32x4;
typedef __attribute__((ext_vector_type(2))) unsigned int uint2v;
typedef unsigned short ushort_t;

#define S_LEN 2048
#define D_DIM 1024
#define NH 16
#define DK 64
#define BATCH 2
#define M_ROWS (BATCH * S_LEN)   // 4096
#define BK 32

__device__ inline ushort_t f2bf(float f) {
    union { float f; uint32_t u; } v; v.f = f;
    uint32_t r = v.u + 0x7fffu + ((v.u >> 16) & 1u);  // RNE
    return (ushort_t)(r >> 16);
}

__device__ __forceinline__ ushort_t bfc(float f) {
    __hip_bfloat16 h = __float2bfloat16(f);          // HW cvt path
    return __builtin_bit_cast(ushort_t, h);
}

__device__ __forceinline__ void glds16(const ushort_t* g, ushort_t* l) {
    __builtin_amdgcn_global_load_lds(
        (const __attribute__((address_space(1))) uint32_t*)g,
        (__attribute__((address_space(3))) uint32_t*)l,
        16, 0, 0);
}

#if __has_builtin(__builtin_amdgcn_permlane16_swap) && __has_builtin(__builtin_amdgcn_permlane32_swap)
#define HAS_PLSWAP 1
#else
#define HAS_PLSWAP 0
#endif

// cross-lane reduce over the 4 16-lane groups (lanes l, l^16, l^32, l^48)
__device__ __forceinline__ float red_max4(float x) {
#if HAS_PLSWAP
    uint2v a = __builtin_amdgcn_permlane16_swap(__float_as_uint(x), __float_as_uint(x), false, false);
    float y = fmaxf(__uint_as_float(a.x), __uint_as_float(a.y));
    uint2v b = __builtin_amdgcn_permlane32_swap(__float_as_uint(y), __float_as_uint(y), false, false);
    return fmaxf(__uint_as_float(b.x), __uint_as_float(b.y));
#else
    x = fmaxf(x, __shfl_xor(x, 16));
    return fmaxf(x, __shfl_xor(x, 32));
#endif
}
__device__ __forceinline__ float red_sum4(float x) {
#if HAS_PLSWAP
    uint2v a = __builtin_amdgcn_permlane16_swap(__float_as_uint(x), __float_as_uint(x), false, false);
    float y = __uint_as_float(a.x) + __uint_as_float(a.y);
    uint2v b = __builtin_amdgcn_permlane32_swap(__float_as_uint(y), __float_as_uint(y), false, false);
    return __uint_as_float(b.x) + __uint_as_float(b.y);
#else
    x += __shfl_xor(x, 16);
    return x + __shfl_xor(x, 32);
#endif
}

// T12 route: build PV A-frag words F[0..3] for k-slice ks from packed P words
// wp[n][h] (kv = 16n + 4*(lane>>4) + 2h + {0,1}, q = lane&15).
// Target lane (q,g) word m needs wp[2ks + (g>>1)][m&1] from lane 16*(2(g&1)+(m>>1)) + q.
__device__ __forceinline__ void route_p(const uint32_t wp[4][2], int ks, int lane, uint32_t F[4]) {
#if HAS_PLSWAP
    uint32_t U0 = wp[2 * ks][0],     U1 = wp[2 * ks][1];
    uint32_t V0 = wp[2 * ks + 1][0], V1 = wp[2 * ks + 1][1];
    uint2v t, pa0, pa1, pb0, pb1;
    t = __builtin_amdgcn_permlane32_swap(U0, U0, false, false);   // t.y[0:31] = U0 rows 2,3
    pa0 = __builtin_amdgcn_permlane16_swap(U0, t.y, false, false); // .x=Ua0 .y=Ub0 (lanes 0-31)
    t = __builtin_amdgcn_permlane32_swap(U1, U1, false, false);
    pa1 = __builtin_amdgcn_permlane16_swap(U1, t.y, false, false);
    t = __builtin_amdgcn_permlane32_swap(V0, V0, false, false);   // t.x[32:63] = V0 rows 0,1
    pb0 = __builtin_amdgcn_permlane16_swap(t.x, V0, false, false); // .x=Va0 .y=Vb0 (lanes 32-63)
    t = __builtin_amdgcn_permlane32_swap(V1, V1, false, false);
    pb1 = __builtin_amdgcn_permlane16_swap(t.x, V1, false, false);
    bool lo = lane < 32;
    F[0] = lo ? pa0.x : pb0.x;
    F[1] = lo ? pa1.x : pb1.x;
    F[2] = lo ? pa0.y : pb0.y;
    F[3] = lo ? pa1.y : pb1.y;
#else
    int q = lane & 15, g = lane >> 4;
#pragma unroll
    for (int m = 0; m < 4; m++) {
        int src = 16 * (2 * (g & 1) + (m >> 1)) + q;
        uint32_t xa = (uint32_t)__shfl((int)wp[2 * ks][m & 1], src);
        uint32_t xb = (uint32_t)__shfl((int)wp[2 * ks + 1][m & 1], src);
        F[m] = (g < 2) ? xa : xb;
    }
#endif
}

// ---------------- fp32 -> bf16 convert (vectorized) ----------------
__global__ void cvt_bf16(const float* __restrict__ in, ushort_t* __restrict__ out, int n4) {
    int i = blockIdx.x * blockDim.x + threadIdx.x;
    int stride = gridDim.x * blockDim.x;
    for (int idx = i; idx < n4; idx += stride) {
        float4 v = ((const float4*)in)[idx];
        ushort4 o;
        o.x = f2bf(v.x); o.y = f2bf(v.y); o.z = f2bf(v.z); o.w = f2bf(v.w);
        ((ushort4*)out)[idx] = o;
    }
}

// fused convert of Wq,Wk,Wv into one [3072,1024] bf16 buffer
__global__ void cvt_w3(const float* __restrict__ wq, const float* __restrict__ wk,
                       const float* __restrict__ wv, ushort_t* __restrict__ wqkv) {
    const int seg = (D_DIM * D_DIM) / 4;   // 2^18
    int i = blockIdx.x * blockDim.x + threadIdx.x;
    int stride = gridDim.x * blockDim.x;
    for (int idx = i; idx < 3 * seg; idx += stride) {
        int sel = idx >> 18;
        int id = idx & (seg - 1);
        const float* src = sel == 0 ? wq : (sel == 1 ? wk : wv);
        float4 v = ((const float4*)src)[id];
        ushort4 o;
        o.x = f2bf(v.x); o.y = f2bf(v.y); o.z = f2bf(v.z); o.w = f2bf(v.w);
        ((ushort4*)wqkv)[sel * seg + id] = o;
    }
}

// ---------------- GEMM: C = A[M,K] * Bw[N,K]^T + bias ----------------
template<int MODE, int BMt, int BNt>
__global__ __launch_bounds__(256) void gemm_bt(const ushort_t* __restrict__ A,
                                               const ushort_t* __restrict__ Bw,
                                               const float* __restrict__ b0,
                                               const float* __restrict__ b1,
                                               const float* __restrict__ b2,
                                               void* __restrict__ C0,
                                               void* __restrict__ C1,
                                               void* __restrict__ C2,
                                               int M, int N, int K) {
    constexpr int FM = BMt / 32, FN = BNt / 32;
    constexpr int ACH = BMt / 64, BCH = BNt / 64;
    __shared__ ushort_t As[BMt * BK];
    __shared__ ushort_t Bs[BNt * BK];
    int tid = threadIdx.x;
    int lane = tid & 63;
    int w = tid >> 6;
    int wr = w >> 1, wc = w & 1;
    int ntile = N / BNt;
    int m0 = (blockIdx.x / ntile) * BMt;
    int n0 = (blockIdx.x % ntile) * BNt;
    int lr = lane & 15;
    int lk = (lane >> 4) * 8;
    int srow = lane >> 2;            // 0..15
    int scol = (lane & 3) * 8;

    f32x4 acc[FM][FN] = {};

    for (int kt = 0; kt < K; kt += BK) {
        __syncthreads();
#pragma unroll
        for (int c = 0; c < ACH; c++)
            glds16(&A[(size_t)(m0 + w * (BMt / 4) + c * 16 + srow) * K + kt + scol],
                   &As[(w * (BMt / 4) + c * 16) * BK]);
#pragma unroll
        for (int c = 0; c < BCH; c++)
            glds16(&Bw[(size_t)(n0 + w * (BNt / 4) + c * 16 + srow) * K + kt + scol],
                   &Bs[(w * (BNt / 4) + c * 16) * BK]);
        __syncthreads();

        short8 af[FM], bf[FN];
#pragma unroll
        for (int f = 0; f < FM; f++)
            af[f] = *(const short8*)&As[(wr * (BMt / 2) + f * 16 + lr) * BK + lk];
#pragma unroll
        for (int f = 0; f < FN; f++)
            bf[f] = *(const short8*)&Bs[(wc * (BNt / 2) + f * 16 + lr) * BK + lk];
#pragma unroll
        for (int i = 0; i < FM; i++)
#pragma unroll
            for (int j = 0; j < FN; j++)
                acc[i][j] = __builtin_amdgcn_mfma_f32_16x16x32_bf16(af[i], bf[j], acc[i][j], 0, 0, 0);
    }

    int r0 = (lane >> 4) * 4;
#pragma unroll
    for (int j = 0; j < FN; j++) {
        int ncol = n0 + wc * (BNt / 2) + j * 16 + lr;
        if (MODE == 2) {
            float bv = b0[ncol];
#pragma unroll
            for (int i = 0; i < FM; i++) {
                int mbase = m0 + wr * (BMt / 2) + i * 16 + r0;
#pragma unroll
                for (int r = 0; r < 4; r++)
                    ((float*)C0)[(size_t)(mbase + r) * N + ncol] = acc[i][j][r] + bv;
            }
        } else {
            int sel = n0 >> 10;                    // block-uniform
            const float* bp = sel == 0 ? b0 : (sel == 1 ? b1 : b2);
            int nc = ncol & 1023;
            float bv = bp[nc];
            int hh = nc >> 6, dk = nc & 63;
            ushort_t* Co = (ushort_t*)(sel == 0 ? C0 : (sel == 1 ? C1 : C2));
#pragma unroll
            for (int i = 0; i < FM; i++) {
                int mbase = m0 + wr * (BMt / 2) + i * 16 + r0;
                int bb = mbase >> 11, ss = mbase & 2047;
                if (sel == 2) {
                    ushort4 pk;
                    pk.x = f2bf(acc[i][j][0] + bv);
                    pk.y = f2bf(acc[i][j][1] + bv);
                    pk.z = f2bf(acc[i][j][2] + bv);
                    pk.w = f2bf(acc[i][j][3] + bv);
                    size_t idx = ((size_t)(bb * NH + hh) * DK + dk) * S_LEN + ss;
                    *(ushort4*)&Co[idx] = pk;
                } else {
#pragma unroll
                    for (int r = 0; r < 4; r++) {
                        size_t idx = ((size_t)(bb * NH + hh) * S_LEN + (ss + r)) * DK + dk;
                        Co[idx] = f2bf(acc[i][j][r] + bv);
                    }
                }
            }
        }
    }
}

// ---------------- Flash attention (causal) ----------------
// Grid (bh=32, y=32). qt = balanced permutation of y so each CU's 4 blocks
// (ids c, c+256, c+512, c+768 under round-robin) sum to 66 kv-tile-units.
// One 64-row q-tile per block; wave w owns frag rows q0+16w..+15.
// K/V: [2][64][64] XOR-swizzled dbuf (32 KB total -> 4 blocks/CU).
// P never touches LDS: packed bf16 + permlane-swap routing (T12).
#define CSC 0.1803368801f   // 0.125 * log2(e)

__global__ __launch_bounds__(256) void attn_fwd(const ushort_t* __restrict__ Q,
                                                const ushort_t* __restrict__ K,
                                                const ushort_t* __restrict__ Vt,
                                                ushort_t* __restrict__ Oa) {
    __shared__ ushort_t Ks[2][64 * 64];
    __shared__ ushort_t Vs[2][64 * 64];

    int tid = threadIdx.x;
    int lane = tid & 63;
    int w = tid >> 6;
    int bh = blockIdx.x;           // 0..31
    int yy = blockIdx.y;           // 0..31
    int a = yy >> 3, bsel = yy & 7;
    int qt = (a == 0) ? bsel : (a == 1) ? 15 - bsel : (a == 2) ? 16 + bsel : 31 - bsel;
    size_t base = (size_t)bh * S_LEN * DK;
    int q0 = qt * 64;

    int lr = lane & 15;
    int lk = (lane >> 4) * 8;
    int g16 = (lane >> 4) * 16;    // byte col of fragment k-slice
    int r0 = (lane >> 4) * 4;
    int wq = w * 16 + lr;          // this lane's q row (within tile)

    // XOR swizzle: ushort index for (row, byte-col) in a [64][128B] tile
    auto swz = [](int row, int cb) { return (row * 128 + (cb ^ ((row & 7) << 4))) >> 1; };

    // Q fragment (16 rows per wave)
    short8 qf0 = *(const short8*)&Q[base + (size_t)(q0 + wq) * DK + lk];
    short8 qf1 = *(const short8*)&Q[base + (size_t)(q0 + wq) * DK + 32 + lk];

    f32x4 o[4] = {};
    float mrowL = -1e30f, lrow = 0.f;

    int sr = tid >> 3;            // 0..31
    int scb = (tid & 7) * 16;     // byte col
    int sce = (tid & 7) * 8;      // element col

    int NT = qt + 1;

    // prologue: stage tile 0 into buf 0 (swizzled)
    *(uint4*)&Ks[0][swz(sr, scb)]      = *(const uint4*)&K [base + (size_t)sr * DK + sce];
    *(uint4*)&Ks[0][swz(sr + 32, scb)] = *(const uint4*)&K [base + (size_t)(sr + 32) * DK + sce];
    *(uint4*)&Vs[0][swz(sr, scb)]      = *(const uint4*)&Vt[base + (size_t)sr * S_LEN + sce];
    *(uint4*)&Vs[0][swz(sr + 32, scb)] = *(const uint4*)&Vt[base + (size_t)(sr + 32) * S_LEN + sce];
    __syncthreads();

    int cur = 0;
    for (int t = 0; t < NT; ++t) {
        bool last = (t == NT - 1);
        bool diag = (t == qt);
        uint4 kr0, kr1, vr0, vr1;
        if (!last) {
            int tn = t + 1;
            kr0 = *(const uint4*)&K [base + (size_t)(tn * 64 + sr) * DK + sce];
            kr1 = *(const uint4*)&K [base + (size_t)(tn * 64 + sr + 32) * DK + sce];
            vr0 = *(const uint4*)&Vt[base + (size_t)sr * S_LEN + tn * 64 + sce];
            vr1 = *(const uint4*)&Vt[base + (size_t)(sr + 32) * S_LEN + tn * 64 + sce];
        }

        // swapped QK^T: st rows = kv (regs), cols = q (lanes)
        f32x4 st[4] = {};
        __builtin_amdgcn_s_setprio(1);
#pragma unroll
        for (int n = 0; n < 4; n++) {
            if (!diag || n <= w) {   // skip fully-masked kv frags on diagonal
                short8 kf0 = *(const short8*)&Ks[cur][swz(n * 16 + lr, g16)];
                short8 kf1 = *(const short8*)&Ks[cur][swz(n * 16 + lr, 64 + g16)];
                st[n] = __builtin_amdgcn_mfma_f32_16x16x32_bf16(kf0, qf0, st[n], 0, 0, 0);
                st[n] = __builtin_amdgcn_mfma_f32_16x16x32_bf16(kf1, qf1, st[n], 0, 0, 0);
            }
        }
        __builtin_amdgcn_s_setprio(0);

        if (diag) {   // causal mask within diagonal tile
#pragma unroll
            for (int n = 0; n < 4; n++)
#pragma unroll
                for (int i = 0; i < 4; i++)
                    if (16 * n + r0 + i > wq) st[n][i] = -1e30f;
        }

        // per-lane softmax (q = lr), reduce across 4 lane-groups
        float mx = fmaxf(
            fmaxf(fmaxf(fmaxf(st[0][0], st[0][1]), fmaxf(st[0][2], st[0][3])),
                  fmaxf(fmaxf(st[1][0], st[1][1]), fmaxf(st[1][2], st[1][3]))),
            fmaxf(fmaxf(fmaxf(st[2][0], st[2][1]), fmaxf(st[2][2], st[2][3])),
                  fmaxf(fmaxf(st[3][0], st[3][1]), fmaxf(st[3][2], st[3][3]))));
        float mxL = red_max4(mx) * CSC;

        bool skip = __all(mxL <= mrowL + 8.0f);   // T13 defer-max
        float corr = 1.0f;
        float mnewL = mrowL;
        if (!skip) {
            mnewL = fmaxf(mrowL, mxL);
            corr = exp2f(mrowL - mnewL);
            mrowL = mnewL;
        }

        float psum = 0.f;
        uint32_t wp[4][2];
#pragma unroll
        for (int n = 0; n < 4; n++) {
#pragma unroll
            for (int i = 0; i < 4; i++) {
                float p = exp2f(fmaf(st[n][i], CSC, -mnewL));
                st[n][i] = p;
                psum += p;
            }
            wp[n][0] = (uint32_t)bfc(st[n][0]) | ((uint32_t)bfc(st[n][1]) << 16);
            wp[n][1] = (uint32_t)bfc(st[n][2]) | ((uint32_t)bfc(st[n][3]) << 16);
        }
        psum = red_sum4(psum);

        if (skip) {
            lrow += psum;
        } else {
            lrow = lrow * corr + psum;
            float cb[4];
#pragma unroll
            for (int i = 0; i < 4; i++) cb[i] = __shfl(corr, r0 + i);
#pragma unroll
            for (int d = 0; d < 4; d++)
#pragma unroll
                for (int i = 0; i < 4; i++) o[d][i] *= cb[i];
        }

        // PV: O += P V, P frags routed in-register
#pragma unroll
        for (int ks = 0; ks < 2; ks++) {
            if (diag && 32 * ks > w * 16 + 15) continue;  // slice fully masked
            uint32_t F[4];
            route_p(wp, ks, lane, F);
            union { uint32_t u[4]; short8 s; } pu;
            pu.u[0] = F[0]; pu.u[1] = F[1]; pu.u[2] = F[2]; pu.u[3] = F[3];
            short8 pf = pu.s;
            __builtin_amdgcn_s_setprio(1);
#pragma unroll
            for (int d = 0; d < 4; d++) {
                short8 vf = *(const short8*)&Vs[cur][swz(d * 16 + lr, ks * 64 + g16)];
                o[d] = __builtin_amdgcn_mfma_f32_16x16x32_bf16(pf, vf, o[d], 0, 0, 0);
            }
            __builtin_amdgcn_s_setprio(0);
        }

        if (!last) {
            *(uint4*)&Ks[cur ^ 1][swz(sr, scb)]      = kr0;
            *(uint4*)&Ks[cur ^ 1][swz(sr + 32, scb)] = kr1;
            *(uint4*)&Vs[cur ^ 1][swz(sr, scb)]      = vr0;
            *(uint4*)&Vs[cur ^ 1][swz(sr + 32, scb)] = vr1;
        }
        __syncthreads();
        cur ^= 1;
    }

    // epilogue: out[b, s, h*64+dk] bf16
    int b = bh >> 4, h = bh & 15;
    float lb[4];
#pragma unroll
    for (int i = 0; i < 4; i++) lb[i] = __shfl(lrow, r0 + i);
#pragma unroll
    for (int d = 0; d < 4; d++)
#pragma unroll
        for (int i = 0; i < 4; i++) {
            int qq = q0 + w * 16 + r0 + i;
            int dk = d * 16 + lr;
            size_t idx = ((size_t)(b * S_LEN + qq)) * D_DIM + h * DK + dk;
            Oa[idx] = bfc(o[d][i] / lb[i]);
        }
}

// ---------------- launch ----------------
extern "C" void kernel_launch(void* const* d_in, const int* in_sizes, int n_in,
                              void* d_out, int out_size, void* d_ws, size_t ws_size,
                              hipStream_t stream) {
    const float* X  = (const float*)d_in[0];
    const float* Wq = (const float*)d_in[1];
    const float* bq = (const float*)d_in[2];
    const float* Wk = (const float*)d_in[3];
    const float* bk = (const float*)d_in[4];
    const float* Wv = (const float*)d_in[5];
    const float* bv = (const float*)d_in[6];
    const float* Wo = (const float*)d_in[7];
    const float* bo = (const float*)d_in[8];
    float* out = (float*)d_out;

    char* ws = (char*)d_ws;
    ushort_t* Xb    = (ushort_t*)ws;                        // 8 MiB [M,D] bf16 (later: attn out)
    ushort_t* Wqkvb = (ushort_t*)(ws + (8u  << 20));        // 6 MiB [3072,1024]; later Wo reuses
    ushort_t* Qb    = (ushort_t*)(ws + (14u << 20));        // 8 MiB [b,h,s,dk]
    ushort_t* Kb    = (ushort_t*)(ws + (22u << 20));        // 8 MiB [b,h,s,dk]
    ushort_t* Vtb   = (ushort_t*)(ws + (30u << 20));        // 8 MiB [b,h,dk,s]
    ushort_t* Wob   = Wqkvb;                                // reuse after QKV gemm
    ushort_t* Ab    = Xb;                                   // attn out reuses X slot

    const int M = M_ROWS;
    int nX4 = (M * D_DIM) / 4;
    int nW4 = (D_DIM * D_DIM) / 4;

    cvt_bf16<<<2048, 256, 0, stream>>>(X, Xb, nX4);
    cvt_w3<<<2048, 256, 0, stream>>>(Wq, Wk, Wv, Wqkvb);

    // fused QKV: 32 x 24 = 768 blocks (3/CU)
    gemm_bt<3, 128, 128><<<dim3((M / 128) * (3072 / 128)), 256, 0, stream>>>(
        Xb, Wqkvb, bq, bk, bv, Qb, Kb, Vtb, M, 3072, D_DIM);

    cvt_bf16<<<2048, 256, 0, stream>>>(Wo, Wob, nW4);

    dim3 agrid(BATCH * NH, 32);   // 1024 blocks, 4/CU
    attn_fwd<<<agrid, 256, 0, stream>>>(Qb, Kb, Vtb, Ab);

    // Wo gemm: 64x128 tiles -> 512 blocks (2/CU)
    gemm_bt<2, 64, 128><<<dim3((M / 64) * (D_DIM / 128)), 256, 0, stream>>>(
        Ab, Wob, bo, bo, bo, out, out, out, M, D_DIM, D_DIM);
}

// Round 7
// 133.058 us; speedup vs baseline: 1.9943x; 1.0144x over previous
//
#include <hip/hip_runtime.h>
#include <hip/hip_bf16.h>
#include <cstdint>

typedef __attribute__((ext_vector_type(8))) short short8;
typedef __attribute__((ext_vector_type(4))) float f32x4;
typedef __attribute__((ext_vector_type(2))) unsigned int uint2v;
typedef unsigned short ushort_t;

#define S_LEN 2048
#define D_DIM 1024
#define NH 16
#define DK 64
#define BATCH 2
#define M_ROWS (BATCH * S_LEN)   // 4096
#define BK 32

__device__ inline ushort_t f2bf(float f) {
    union { float f; uint32_t u; } v; v.f = f;
    uint32_t r = v.u + 0x7fffu + ((v.u >> 16) & 1u);  // RNE
    return (ushort_t)(r >> 16);
}

__device__ __forceinline__ ushort_t bfc(float f) {
    __hip_bfloat16 h = __float2bfloat16(f);          // HW cvt path
    return __builtin_bit_cast(ushort_t, h);
}

__device__ __forceinline__ void glds16(const ushort_t* g, ushort_t* l) {
    __builtin_amdgcn_global_load_lds(
        (const __attribute__((address_space(1))) uint32_t*)g,
        (__attribute__((address_space(3))) uint32_t*)l,
        16, 0, 0);
}

#if __has_builtin(__builtin_amdgcn_permlane16_swap) && __has_builtin(__builtin_amdgcn_permlane32_swap)
#define HAS_PLSWAP 1
#else
#define HAS_PLSWAP 0
#endif

// cross-lane reduce over the 4 16-lane groups (lanes l, l^16, l^32, l^48)
__device__ __forceinline__ float red_max4(float x) {
#if HAS_PLSWAP
    uint2v a = __builtin_amdgcn_permlane16_swap(__float_as_uint(x), __float_as_uint(x), false, false);
    float y = fmaxf(__uint_as_float(a.x), __uint_as_float(a.y));
    uint2v b = __builtin_amdgcn_permlane32_swap(__float_as_uint(y), __float_as_uint(y), false, false);
    return fmaxf(__uint_as_float(b.x), __uint_as_float(b.y));
#else
    x = fmaxf(x, __shfl_xor(x, 16));
    return fmaxf(x, __shfl_xor(x, 32));
#endif
}
__device__ __forceinline__ float red_sum4(float x) {
#if HAS_PLSWAP
    uint2v a = __builtin_amdgcn_permlane16_swap(__float_as_uint(x), __float_as_uint(x), false, false);
    float y = __uint_as_float(a.x) + __uint_as_float(a.y);
    uint2v b = __builtin_amdgcn_permlane32_swap(__float_as_uint(y), __float_as_uint(y), false, false);
    return __uint_as_float(b.x) + __uint_as_float(b.y);
#else
    x += __shfl_xor(x, 16);
    return x + __shfl_xor(x, 32);
#endif
}

// T12 route: build PV A-frag words F[0..3] for k-slice ks from packed P words
// wp[n][h] (kv = 16n + 4*(lane>>4) + 2h + {0,1}, q = lane&15).
__device__ __forceinline__ void route_p(const uint32_t wp[4][2], int ks, int lane, uint32_t F[4]) {
#if HAS_PLSWAP
    uint32_t U0 = wp[2 * ks][0],     U1 = wp[2 * ks][1];
    uint32_t V0 = wp[2 * ks + 1][0], V1 = wp[2 * ks + 1][1];
    uint2v t, pa0, pa1, pb0, pb1;
    t = __builtin_amdgcn_permlane32_swap(U0, U0, false, false);
    pa0 = __builtin_amdgcn_permlane16_swap(U0, t.y, false, false);
    t = __builtin_amdgcn_permlane32_swap(U1, U1, false, false);
    pa1 = __builtin_amdgcn_permlane16_swap(U1, t.y, false, false);
    t = __builtin_amdgcn_permlane32_swap(V0, V0, false, false);
    pb0 = __builtin_amdgcn_permlane16_swap(t.x, V0, false, false);
    t = __builtin_amdgcn_permlane32_swap(V1, V1, false, false);
    pb1 = __builtin_amdgcn_permlane16_swap(t.x, V1, false, false);
    bool lo = lane < 32;
    F[0] = lo ? pa0.x : pb0.x;
    F[1] = lo ? pa1.x : pb1.x;
    F[2] = lo ? pa0.y : pb0.y;
    F[3] = lo ? pa1.y : pb1.y;
#else
    int q = lane & 15, g = lane >> 4;
#pragma unroll
    for (int m = 0; m < 4; m++) {
        int src = 16 * (2 * (g & 1) + (m >> 1)) + q;
        uint32_t xa = (uint32_t)__shfl((int)wp[2 * ks][m & 1], src);
        uint32_t xb = (uint32_t)__shfl((int)wp[2 * ks + 1][m & 1], src);
        F[m] = (g < 2) ? xa : xb;
    }
#endif
}

// ---------------- fp32 -> bf16 convert (vectorized) ----------------
__global__ void cvt_bf16(const float* __restrict__ in, ushort_t* __restrict__ out, int n4) {
    int i = blockIdx.x * blockDim.x + threadIdx.x;
    int stride = gridDim.x * blockDim.x;
    for (int idx = i; idx < n4; idx += stride) {
        float4 v = ((const float4*)in)[idx];
        ushort4 o;
        o.x = f2bf(v.x); o.y = f2bf(v.y); o.z = f2bf(v.z); o.w = f2bf(v.w);
        ((ushort4*)out)[idx] = o;
    }
}

// fused convert of Wq,Wk,Wv into one [3072,1024] bf16 buffer
__global__ void cvt_w3(const float* __restrict__ wq, const float* __restrict__ wk,
                       const float* __restrict__ wv, ushort_t* __restrict__ wqkv) {
    const int seg = (D_DIM * D_DIM) / 4;   // 2^18
    int i = blockIdx.x * blockDim.x + threadIdx.x;
    int stride = gridDim.x * blockDim.x;
    for (int idx = i; idx < 3 * seg; idx += stride) {
        int sel = idx >> 18;
        int id = idx & (seg - 1);
        const float* src = sel == 0 ? wq : (sel == 1 ? wk : wv);
        float4 v = ((const float4*)src)[id];
        ushort4 o;
        o.x = f2bf(v.x); o.y = f2bf(v.y); o.z = f2bf(v.z); o.w = f2bf(v.w);
        ((ushort4*)wqkv)[sel * seg + id] = o;
    }
}

// ---------------- GEMM: C = A[M,K] * Bw[N,K]^T + bias ----------------
// T1: bijective XCD remap (grid must be a multiple of 8 blocks).
template<int MODE, int BMt, int BNt>
__global__ __launch_bounds__(256) void gemm_bt(const ushort_t* __restrict__ A,
                                               const ushort_t* __restrict__ Bw,
                                               const float* __restrict__ b0,
                                               const float* __restrict__ b1,
                                               const float* __restrict__ b2,
                                               void* __restrict__ C0,
                                               void* __restrict__ C1,
                                               void* __restrict__ C2,
                                               int M, int N, int K) {
    constexpr int FM = BMt / 32, FN = BNt / 32;
    constexpr int ACH = BMt / 64, BCH = BNt / 64;
    __shared__ ushort_t As[BMt * BK];
    __shared__ ushort_t Bs[BNt * BK];
    int tid = threadIdx.x;
    int lane = tid & 63;
    int w = tid >> 6;
    int wr = w >> 1, wc = w & 1;
    // XCD-aware remap: consecutive logical tiles (same A panel) -> same XCD L2
    int nwg = gridDim.x;
    int bx = (blockIdx.x & 7) * (nwg >> 3) + (blockIdx.x >> 3);
    int ntile = N / BNt;
    int m0 = (bx / ntile) * BMt;
    int n0 = (bx % ntile) * BNt;
    int lr = lane & 15;
    int lk = (lane >> 4) * 8;
    int srow = lane >> 2;            // 0..15
    int scol = (lane & 3) * 8;

    f32x4 acc[FM][FN] = {};

    for (int kt = 0; kt < K; kt += BK) {
        __syncthreads();
#pragma unroll
        for (int c = 0; c < ACH; c++)
            glds16(&A[(size_t)(m0 + w * (BMt / 4) + c * 16 + srow) * K + kt + scol],
                   &As[(w * (BMt / 4) + c * 16) * BK]);
#pragma unroll
        for (int c = 0; c < BCH; c++)
            glds16(&Bw[(size_t)(n0 + w * (BNt / 4) + c * 16 + srow) * K + kt + scol],
                   &Bs[(w * (BNt / 4) + c * 16) * BK]);
        __syncthreads();

        short8 af[FM], bf[FN];
#pragma unroll
        for (int f = 0; f < FM; f++)
            af[f] = *(const short8*)&As[(wr * (BMt / 2) + f * 16 + lr) * BK + lk];
#pragma unroll
        for (int f = 0; f < FN; f++)
            bf[f] = *(const short8*)&Bs[(wc * (BNt / 2) + f * 16 + lr) * BK + lk];
#pragma unroll
        for (int i = 0; i < FM; i++)
#pragma unroll
            for (int j = 0; j < FN; j++)
                acc[i][j] = __builtin_amdgcn_mfma_f32_16x16x32_bf16(af[i], bf[j], acc[i][j], 0, 0, 0);
    }

    int r0 = (lane >> 4) * 4;
#pragma unroll
    for (int j = 0; j < FN; j++) {
        int ncol = n0 + wc * (BNt / 2) + j * 16 + lr;
        if (MODE == 2) {
            float bv = b0[ncol];
#pragma unroll
            for (int i = 0; i < FM; i++) {
                int mbase = m0 + wr * (BMt / 2) + i * 16 + r0;
#pragma unroll
                for (int r = 0; r < 4; r++)
                    ((float*)C0)[(size_t)(mbase + r) * N + ncol] = acc[i][j][r] + bv;
            }
        } else {
            int sel = n0 >> 10;                    // block-uniform
            const float* bp = sel == 0 ? b0 : (sel == 1 ? b1 : b2);
            int nc = ncol & 1023;
            float bv = bp[nc];
            int hh = nc >> 6, dk = nc & 63;
            ushort_t* Co = (ushort_t*)(sel == 0 ? C0 : (sel == 1 ? C1 : C2));
#pragma unroll
            for (int i = 0; i < FM; i++) {
                int mbase = m0 + wr * (BMt / 2) + i * 16 + r0;
                int bb = mbase >> 11, ss = mbase & 2047;
                if (sel == 2) {
                    ushort4 pk;
                    pk.x = f2bf(acc[i][j][0] + bv);
                    pk.y = f2bf(acc[i][j][1] + bv);
                    pk.z = f2bf(acc[i][j][2] + bv);
                    pk.w = f2bf(acc[i][j][3] + bv);
                    size_t idx = ((size_t)(bb * NH + hh) * DK + dk) * S_LEN + ss;
                    *(ushort4*)&Co[idx] = pk;
                } else {
#pragma unroll
                    for (int r = 0; r < 4; r++) {
                        size_t idx = ((size_t)(bb * NH + hh) * S_LEN + (ss + r)) * DK + dk;
                        Co[idx] = f2bf(acc[i][j][r] + bv);
                    }
                }
            }
        }
    }
}

// ---------------- Flash attention (causal) ----------------
// ROUND-5 VERIFIED VERSION (reverted). Grid (bh=32, y=32). qt = balanced
// permutation of y. One 64-row q-tile per block; wave w owns rows q0+16w..+15.
// K/V: [2][64][64] XOR-swizzled dbuf (32 KB). P in-register (T12 route).
#define CSC 0.1803368801f   // 0.125 * log2(e)

__global__ __launch_bounds__(256) void attn_fwd(const ushort_t* __restrict__ Q,
                                                const ushort_t* __restrict__ K,
                                                const ushort_t* __restrict__ Vt,
                                                ushort_t* __restrict__ Oa) {
    __shared__ ushort_t Ks[2][64 * 64];
    __shared__ ushort_t Vs[2][64 * 64];

    int tid = threadIdx.x;
    int lane = tid & 63;
    int w = tid >> 6;
    int bh = blockIdx.x;           // 0..31
    int yy = blockIdx.y;           // 0..31
    int a = yy >> 3, bsel = yy & 7;
    int qt = (a == 0) ? bsel : (a == 1) ? 15 - bsel : (a == 2) ? 16 + bsel : 31 - bsel;
    size_t base = (size_t)bh * S_LEN * DK;
    int q0 = qt * 64;

    int lr = lane & 15;
    int lk = (lane >> 4) * 8;
    int g16 = (lane >> 4) * 16;    // byte col of fragment k-slice
    int r0 = (lane >> 4) * 4;
    int wq = w * 16 + lr;          // this lane's q row (within tile)

    // XOR swizzle: ushort index for (row, byte-col) in a [64][128B] tile
    auto swz = [](int row, int cb) { return (row * 128 + (cb ^ ((row & 7) << 4))) >> 1; };

    // Q fragment (16 rows per wave)
    short8 qf0 = *(const short8*)&Q[base + (size_t)(q0 + wq) * DK + lk];
    short8 qf1 = *(const short8*)&Q[base + (size_t)(q0 + wq) * DK + 32 + lk];

    f32x4 o[4] = {};
    float mrowL = -1e30f, lrow = 0.f;

    int sr = tid >> 3;            // 0..31
    int scb = (tid & 7) * 16;     // byte col
    int sce = (tid & 7) * 8;      // element col

    int NT = qt + 1;

    // prologue: stage tile 0 into buf 0 (swizzled)
    *(uint4*)&Ks[0][swz(sr, scb)]      = *(const uint4*)&K [base + (size_t)sr * DK + sce];
    *(uint4*)&Ks[0][swz(sr + 32, scb)] = *(const uint4*)&K [base + (size_t)(sr + 32) * DK + sce];
    *(uint4*)&Vs[0][swz(sr, scb)]      = *(const uint4*)&Vt[base + (size_t)sr * S_LEN + sce];
    *(uint4*)&Vs[0][swz(sr + 32, scb)] = *(const uint4*)&Vt[base + (size_t)(sr + 32) * S_LEN + sce];
    __syncthreads();

    int cur = 0;
    for (int t = 0; t < NT; ++t) {
        bool last = (t == NT - 1);
        bool diag = (t == qt);
        uint4 kr0, kr1, vr0, vr1;
        if (!last) {
            int tn = t + 1;
            kr0 = *(const uint4*)&K [base + (size_t)(tn * 64 + sr) * DK + sce];
            kr1 = *(const uint4*)&K [base + (size_t)(tn * 64 + sr + 32) * DK + sce];
            vr0 = *(const uint4*)&Vt[base + (size_t)sr * S_LEN + tn * 64 + sce];
            vr1 = *(const uint4*)&Vt[base + (size_t)(sr + 32) * S_LEN + tn * 64 + sce];
        }

        // swapped QK^T: st rows = kv (regs), cols = q (lanes)
        f32x4 st[4] = {};
        __builtin_amdgcn_s_setprio(1);
#pragma unroll
        for (int n = 0; n < 4; n++) {
            if (!diag || n <= w) {   // skip fully-masked kv frags on diagonal
                short8 kf0 = *(const short8*)&Ks[cur][swz(n * 16 + lr, g16)];
                short8 kf1 = *(const short8*)&Ks[cur][swz(n * 16 + lr, 64 + g16)];
                st[n] = __builtin_amdgcn_mfma_f32_16x16x32_bf16(kf0, qf0, st[n], 0, 0, 0);
                st[n] = __builtin_amdgcn_mfma_f32_16x16x32_bf16(kf1, qf1, st[n], 0, 0, 0);
            }
        }
        __builtin_amdgcn_s_setprio(0);

        if (diag) {   // causal mask within diagonal tile
#pragma unroll
            for (int n = 0; n < 4; n++)
#pragma unroll
                for (int i = 0; i < 4; i++)
                    if (16 * n + r0 + i > wq) st[n][i] = -1e30f;
        }

        // per-lane softmax (q = lr), reduce across 4 lane-groups
        float mx = fmaxf(
            fmaxf(fmaxf(fmaxf(st[0][0], st[0][1]), fmaxf(st[0][2], st[0][3])),
                  fmaxf(fmaxf(st[1][0], st[1][1]), fmaxf(st[1][2], st[1][3]))),
            fmaxf(fmaxf(fmaxf(st[2][0], st[2][1]), fmaxf(st[2][2], st[2][3])),
                  fmaxf(fmaxf(st[3][0], st[3][1]), fmaxf(st[3][2], st[3][3]))));
        float mxL = red_max4(mx) * CSC;

        bool skip = __all(mxL <= mrowL + 8.0f);   // T13 defer-max
        float corr = 1.0f;
        float mnewL = mrowL;
        if (!skip) {
            mnewL = fmaxf(mrowL, mxL);
            corr = exp2f(mrowL - mnewL);
            mrowL = mnewL;
        }

        float psum = 0.f;
        uint32_t wp[4][2];
#pragma unroll
        for (int n = 0; n < 4; n++) {
#pragma unroll
            for (int i = 0; i < 4; i++) {
                float p = exp2f(fmaf(st[n][i], CSC, -mnewL));
                st[n][i] = p;
                psum += p;
            }
            wp[n][0] = (uint32_t)bfc(st[n][0]) | ((uint32_t)bfc(st[n][1]) << 16);
            wp[n][1] = (uint32_t)bfc(st[n][2]) | ((uint32_t)bfc(st[n][3]) << 16);
        }
        psum = red_sum4(psum);

        if (skip) {
            lrow += psum;
        } else {
            lrow = lrow * corr + psum;
            float cb[4];
#pragma unroll
            for (int i = 0; i < 4; i++) cb[i] = __shfl(corr, r0 + i);
#pragma unroll
            for (int d = 0; d < 4; d++)
#pragma unroll
                for (int i = 0; i < 4; i++) o[d][i] *= cb[i];
        }

        // PV: O += P V, P frags routed in-register
#pragma unroll
        for (int ks = 0; ks < 2; ks++) {
            if (diag && 32 * ks > w * 16 + 15) continue;  // slice fully masked
            uint32_t F[4];
            route_p(wp, ks, lane, F);
            union { uint32_t u[4]; short8 s; } pu;
            pu.u[0] = F[0]; pu.u[1] = F[1]; pu.u[2] = F[2]; pu.u[3] = F[3];
            short8 pf = pu.s;
            __builtin_amdgcn_s_setprio(1);
#pragma unroll
            for (int d = 0; d < 4; d++) {
                short8 vf = *(const short8*)&Vs[cur][swz(d * 16 + lr, ks * 64 + g16)];
                o[d] = __builtin_amdgcn_mfma_f32_16x16x32_bf16(pf, vf, o[d], 0, 0, 0);
            }
            __builtin_amdgcn_s_setprio(0);
        }

        if (!last) {
            *(uint4*)&Ks[cur ^ 1][swz(sr, scb)]      = kr0;
            *(uint4*)&Ks[cur ^ 1][swz(sr + 32, scb)] = kr1;
            *(uint4*)&Vs[cur ^ 1][swz(sr, scb)]      = vr0;
            *(uint4*)&Vs[cur ^ 1][swz(sr + 32, scb)] = vr1;
        }
        __syncthreads();
        cur ^= 1;
    }

    // epilogue: out[b, s, h*64+dk] bf16
    int b = bh >> 4, h = bh & 15;
    float lb[4];
#pragma unroll
    for (int i = 0; i < 4; i++) lb[i] = __shfl(lrow, r0 + i);
#pragma unroll
    for (int d = 0; d < 4; d++)
#pragma unroll
        for (int i = 0; i < 4; i++) {
            int qq = q0 + w * 16 + r0 + i;
            int dk = d * 16 + lr;
            size_t idx = ((size_t)(b * S_LEN + qq)) * D_DIM + h * DK + dk;
            Oa[idx] = bfc(o[d][i] / lb[i]);
        }
}

// ---------------- launch ----------------
extern "C" void kernel_launch(void* const* d_in, const int* in_sizes, int n_in,
                              void* d_out, int out_size, void* d_ws, size_t ws_size,
                              hipStream_t stream) {
    const float* X  = (const float*)d_in[0];
    const float* Wq = (const float*)d_in[1];
    const float* bq = (const float*)d_in[2];
    const float* Wk = (const float*)d_in[3];
    const float* bk = (const float*)d_in[4];
    const float* Wv = (const float*)d_in[5];
    const float* bv = (const float*)d_in[6];
    const float* Wo = (const float*)d_in[7];
    const float* bo = (const float*)d_in[8];
    float* out = (float*)d_out;

    char* ws = (char*)d_ws;
    ushort_t* Xb    = (ushort_t*)ws;                        // 8 MiB [M,D] bf16 (later: attn out)
    ushort_t* Wqkvb = (ushort_t*)(ws + (8u  << 20));        // 6 MiB [3072,1024]; later Wo reuses
    ushort_t* Qb    = (ushort_t*)(ws + (14u << 20));        // 8 MiB [b,h,s,dk]
    ushort_t* Kb    = (ushort_t*)(ws + (22u << 20));        // 8 MiB [b,h,s,dk]
    ushort_t* Vtb   = (ushort_t*)(ws + (30u << 20));        // 8 MiB [b,h,dk,s]
    ushort_t* Wob   = Wqkvb;                                // reuse after QKV gemm
    ushort_t* Ab    = Xb;                                   // attn out reuses X slot

    const int M = M_ROWS;
    int nX4 = (M * D_DIM) / 4;
    int nW4 = (D_DIM * D_DIM) / 4;

    cvt_bf16<<<2048, 256, 0, stream>>>(X, Xb, nX4);
    cvt_w3<<<2048, 256, 0, stream>>>(Wq, Wk, Wv, Wqkvb);

    // fused QKV: 32 x 24 = 768 blocks (3/CU)
    gemm_bt<3, 128, 128><<<dim3((M / 128) * (3072 / 128)), 256, 0, stream>>>(
        Xb, Wqkvb, bq, bk, bv, Qb, Kb, Vtb, M, 3072, D_DIM);

    cvt_bf16<<<2048, 256, 0, stream>>>(Wo, Wob, nW4);

    dim3 agrid(BATCH * NH, 32);   // 1024 blocks, 4/CU, permuted qt balance
    attn_fwd<<<agrid, 256, 0, stream>>>(Qb, Kb, Vtb, Ab);

    // Wo gemm: 64x128 tiles -> 512 blocks (2/CU)
    gemm_bt<2, 64, 128><<<dim3((M / 64) * (D_DIM / 128)), 256, 0, stream>>>(
        Ab, Wob, bo, bo, bo, out, out, out, M, D_DIM, D_DIM);
}